// Round 5
// baseline (484.330 us; speedup 1.0000x reference)
//
#include <hip/hip_runtime.h>

#define NN 20000
#define NE 320000

// ---------------- CSR construction ----------------

__global__ void zero_i32(int* __restrict__ p, int n) {
  int i = blockIdx.x * blockDim.x + threadIdx.x;
  if (i < n) p[i] = 0;
}

__global__ void count_dst(const int* __restrict__ ei, int* __restrict__ counts) {
  int e = blockIdx.x * blockDim.x + threadIdx.x;
  if (e < NE) atomicAdd(&counts[ei[NE + e]], 1);
}

// three-kernel scan
__global__ void scan_local(const int* __restrict__ counts, int* __restrict__ tmp,
                           int* __restrict__ bsum) {
  __shared__ int sh[1024];
  int b = blockIdx.x, t = threadIdx.x, i = b * 1024 + t;
  int v = (i < NN) ? counts[i] : 0;
  sh[t] = v;
  __syncthreads();
  for (int off = 1; off < 1024; off <<= 1) {
    int add = (t >= off) ? sh[t - off] : 0;
    __syncthreads();
    sh[t] += add;
    __syncthreads();
  }
  if (i < NN) tmp[i] = sh[t];
  if (t == 1023) bsum[b] = sh[t];
}

__global__ void scan_bsum(int* __restrict__ bsum, int nb) {
  if (threadIdx.x == 0) {
    int run = 0;
    for (int j = 0; j < nb; ++j) { int v = bsum[j]; bsum[j] = run; run += v; }
  }
}

__global__ void scan_finish(const int* __restrict__ counts, const int* __restrict__ tmp,
                            const int* __restrict__ bsum, int* __restrict__ row_ptr,
                            int* __restrict__ cursor) {
  int i = blockIdx.x * 256 + threadIdx.x;
  if (i == 0) row_ptr[0] = 0;
  if (i < NN) {
    int incl = tmp[i] + bsum[i >> 10];
    row_ptr[i + 1] = incl;
    cursor[i] = incl - counts[i];
  }
}

// scatter: write src id AND reorder edge_attr into CSR position order.
// Removes two levels of indirection from the hot aggregation loops.
__global__ void scatter_edges(const int* __restrict__ ei, const float4* __restrict__ eattr4,
                              int* __restrict__ cursor, int* __restrict__ srcs,
                              float4* __restrict__ ea_r) {
  int e = blockIdx.x * blockDim.x + threadIdx.x;
  if (e < NE) {
    int d = ei[NE + e];
    int pos = atomicAdd(&cursor[d], 1);
    srcs[pos] = ei[e];
    float4 a0 = eattr4[(size_t)e * 4 + 0];
    float4 a1 = eattr4[(size_t)e * 4 + 1];
    float4 a2 = eattr4[(size_t)e * 4 + 2];
    float4 a3 = eattr4[(size_t)e * 4 + 3];
    ea_r[(size_t)pos * 4 + 0] = a0;
    ea_r[(size_t)pos * 4 + 1] = a1;
    ea_r[(size_t)pos * 4 + 2] = a2;
    ea_r[(size_t)pos * 4 + 3] = a3;
  }
}

// ---------------- dual projection GEMM (float4 LDS reads) ----------------

template<int K, int NC, int TMG, int G>
__global__ void gemm_dual_g(const float* __restrict__ A, const float* __restrict__ W1,
                            const float* __restrict__ W2, float* __restrict__ C1,
                            float* __restrict__ C2) {
  constexpr int TM = TMG * G;
  __shared__ float As[TM * K];
  int t = threadIdx.x;
  int n = t & (NC - 1);
  int g = t / NC;
  int m0 = blockIdx.x * TM;
  const float4* A4 = (const float4*)(A + (size_t)m0 * K);
  float4* As4 = (float4*)As;
  for (int idx = t; idx < TM * K / 4; idx += NC * G) As4[idx] = A4[idx];
  __syncthreads();
  float acc1[TMG], acc2[TMG];
#pragma unroll
  for (int m = 0; m < TMG; ++m) { acc1[m] = 0.f; acc2[m] = 0.f; }
  for (int k = 0; k < K; k += 4) {
    float w10 = W1[(k + 0) * NC + n], w11 = W1[(k + 1) * NC + n];
    float w12 = W1[(k + 2) * NC + n], w13 = W1[(k + 3) * NC + n];
    float w20 = W2[(k + 0) * NC + n], w21 = W2[(k + 1) * NC + n];
    float w22 = W2[(k + 2) * NC + n], w23 = W2[(k + 3) * NC + n];
#pragma unroll
    for (int m = 0; m < TMG; ++m) {
      float4 a = *(const float4*)&As[(g * TMG + m) * K + k];
      acc1[m] += a.x * w10 + a.y * w11 + a.z * w12 + a.w * w13;
      acc2[m] += a.x * w20 + a.y * w21 + a.z * w22 + a.w * w23;
    }
  }
#pragma unroll
  for (int m = 0; m < TMG; ++m) {
    size_t row = m0 + g * TMG + m;
    C1[row * NC + n] = acc1[m];
    C2[row * NC + n] = acc2[m];
  }
}

// ---------------- fused attention + aggregation ----------------
// layer 1: block per node, 4 waves; wave covers all 4 heads x 64 ch of one edge
// (lane = head (lane>>4) x 4-ch group). Wave w takes edges beg+w, +4, ...
// We in LDS (not VGPRs: the reg array caused the round-4 occupancy cliff).

__global__ __launch_bounds__(256) void attn_agg1(
    const int* __restrict__ srcs, const int* __restrict__ row_ptr,
    const float4* __restrict__ ea_r, const float* __restrict__ xl,
    const float* __restrict__ xr, const float* __restrict__ We,
    const float* __restrict__ att, const float* __restrict__ bias,
    float* __restrict__ hout) {
  __shared__ float4 weS[16][64];  // [k][col/4]
  int n = blockIdx.x;
  int t = threadIdx.x, w = t >> 6, lane = t & 63;
  for (int idx = t; idx < 16 * 64; idx += 256) {
    int k = idx >> 6, c = idx & 63;
    weS[k][c] = ((const float4*)We)[k * 64 + c];
  }
  int col = (lane >> 4) * 64 + (lane & 15) * 4;
  int c4 = col >> 2;
  float4 at = *(const float4*)(att + col);
  float4 xr4 = *(const float4*)(xr + (size_t)n * 256 + col);
  int beg = row_ptr[n], end = row_ptr[n + 1];
  __syncthreads();

  float m = -1e30f, denom = 0.f;
  float4 acc = make_float4(0.f, 0.f, 0.f, 0.f);

  int i = beg + w;
  int sc = 0;
  float4 xc = make_float4(0.f, 0.f, 0.f, 0.f);
  if (i < end) {
    sc = srcs[i];
    xc = *(const float4*)(xl + (size_t)sc * 256 + col);
  }
  for (; i < end; i += 4) {
    int in = i + 4;
    int sn = 0;
    float4 xn = make_float4(0.f, 0.f, 0.f, 0.f);
    if (in < end) {
      sn = srcs[in];
      xn = *(const float4*)(xl + (size_t)sn * 256 + col);
    }
    const float4* ep = ea_r + (size_t)i * 4;
    float4 e0 = ep[0], e1 = ep[1], e2 = ep[2], e3 = ep[3];
    float4 v;
    v.x = xc.x + xr4.x; v.y = xc.y + xr4.y;
    v.z = xc.z + xr4.z; v.w = xc.w + xr4.w;
    {
      float4 w0 = weS[0][c4], w1 = weS[1][c4], w2 = weS[2][c4], w3 = weS[3][c4];
      v.x += e0.x * w0.x + e0.y * w1.x + e0.z * w2.x + e0.w * w3.x;
      v.y += e0.x * w0.y + e0.y * w1.y + e0.z * w2.y + e0.w * w3.y;
      v.z += e0.x * w0.z + e0.y * w1.z + e0.z * w2.z + e0.w * w3.z;
      v.w += e0.x * w0.w + e0.y * w1.w + e0.z * w2.w + e0.w * w3.w;
    }
    {
      float4 w0 = weS[4][c4], w1 = weS[5][c4], w2 = weS[6][c4], w3 = weS[7][c4];
      v.x += e1.x * w0.x + e1.y * w1.x + e1.z * w2.x + e1.w * w3.x;
      v.y += e1.x * w0.y + e1.y * w1.y + e1.z * w2.y + e1.w * w3.y;
      v.z += e1.x * w0.z + e1.y * w1.z + e1.z * w2.z + e1.w * w3.z;
      v.w += e1.x * w0.w + e1.y * w1.w + e1.z * w2.w + e1.w * w3.w;
    }
    {
      float4 w0 = weS[8][c4], w1 = weS[9][c4], w2 = weS[10][c4], w3 = weS[11][c4];
      v.x += e2.x * w0.x + e2.y * w1.x + e2.z * w2.x + e2.w * w3.x;
      v.y += e2.x * w0.y + e2.y * w1.y + e2.z * w2.y + e2.w * w3.y;
      v.z += e2.x * w0.z + e2.y * w1.z + e2.z * w2.z + e2.w * w3.z;
      v.w += e2.x * w0.w + e2.y * w1.w + e2.z * w2.w + e2.w * w3.w;
    }
    {
      float4 w0 = weS[12][c4], w1 = weS[13][c4], w2 = weS[14][c4], w3 = weS[15][c4];
      v.x += e3.x * w0.x + e3.y * w1.x + e3.z * w2.x + e3.w * w3.x;
      v.y += e3.x * w0.y + e3.y * w1.y + e3.z * w2.y + e3.w * w3.y;
      v.z += e3.x * w0.z + e3.y * w1.z + e3.z * w2.z + e3.w * w3.z;
      v.w += e3.x * w0.w + e3.y * w1.w + e3.z * w2.w + e3.w * w3.w;
    }
    v.x = (v.x > 0.f) ? v.x : 0.2f * v.x;
    v.y = (v.y > 0.f) ? v.y : 0.2f * v.y;
    v.z = (v.z > 0.f) ? v.z : 0.2f * v.z;
    v.w = (v.w > 0.f) ? v.w : 0.2f * v.w;
    float s = at.x * v.x + at.y * v.y + at.z * v.z + at.w * v.w;
#pragma unroll
    for (int off = 8; off >= 1; off >>= 1) s += __shfl_xor(s, off);
    float m_new = fmaxf(m, s);
    float f = __expf(m - m_new);
    float a = __expf(s - m_new);
    denom = denom * f + a;
    acc.x = acc.x * f + a * xc.x; acc.y = acc.y * f + a * xc.y;
    acc.z = acc.z * f + a * xc.z; acc.w = acc.w * f + a * xc.w;
    m = m_new;
    sc = sn; xc = xn;
  }

  // merge 4 waves; reuse weS LDS (all waves past their loops after barrier)
  __syncthreads();
  float* sm = (float*)weS;                // [4][64]
  float* sd = sm + 4 * 64;                // [4][64]
  float4* sa = (float4*)(sd + 4 * 64);    // [4][64]
  sm[w * 64 + lane] = m;
  sd[w * 64 + lane] = denom;
  sa[w * 64 + lane] = acc;
  __syncthreads();
  if (w == 0) {
    float M = sm[lane];
#pragma unroll
    for (int j = 1; j < 4; ++j) M = fmaxf(M, sm[j * 64 + lane]);
    float D = 0.f;
    float4 A = make_float4(0.f, 0.f, 0.f, 0.f);
#pragma unroll
    for (int j = 0; j < 4; ++j) {
      float f = __expf(sm[j * 64 + lane] - M);
      D += sd[j * 64 + lane] * f;
      float4 aj = sa[j * 64 + lane];
      A.x += aj.x * f; A.y += aj.y * f; A.z += aj.z * f; A.w += aj.w * f;
    }
    bool has = (end > beg);
    float4 b4 = *(const float4*)(bias + col);
    float4 o;
    o.x = (has ? A.x / D : 0.f) + b4.x;
    o.y = (has ? A.y / D : 0.f) + b4.y;
    o.z = (has ? A.z / D : 0.f) + b4.z;
    o.w = (has ? A.w / D : 0.f) + b4.w;
    o.x = (o.x > 0.f) ? o.x : (__expf(o.x) - 1.f);
    o.y = (o.y > 0.f) ? o.y : (__expf(o.y) - 1.f);
    o.z = (o.z > 0.f) ? o.z : (__expf(o.z) - 1.f);
    o.w = (o.w > 0.f) ? o.w : (__expf(o.w) - 1.f);
    *(float4*)(hout + (size_t)n * 256 + col) = o;
  }
}

// layer 2: wave per node (4/block); 4 subgroups of 16 lanes, subgroup g takes
// edges beg+g, +4, ...; lane covers 4 channels. We2 in LDS.

__global__ __launch_bounds__(256) void attn_agg2(
    const int* __restrict__ srcs, const int* __restrict__ row_ptr,
    const float4* __restrict__ ea_r, const float* __restrict__ xl,
    const float* __restrict__ xr, const float* __restrict__ We,
    const float* __restrict__ att, const float* __restrict__ bias,
    float* __restrict__ out) {
  __shared__ float4 weS[16][16];  // [k][col/4]
  int t = threadIdx.x, w = t >> 6, lane = t & 63;
  if (t < 256) {
    if (t < 16 * 16) weS[t >> 4][t & 15] = ((const float4*)We)[t];
  }
  int n = blockIdx.x * 4 + w;
  int g = lane >> 4, cb = (lane & 15) * 4;
  int c4 = lane & 15;
  float4 at = *(const float4*)(att + cb);
  float4 xr4 = *(const float4*)(xr + (size_t)n * 64 + cb);
  int beg = row_ptr[n], end = row_ptr[n + 1];
  __syncthreads();

  float m = -1e30f, denom = 0.f;
  float4 acc = make_float4(0.f, 0.f, 0.f, 0.f);

  int i = beg + g;
  int sc = 0;
  float4 xc = make_float4(0.f, 0.f, 0.f, 0.f);
  if (i < end) {
    sc = srcs[i];
    xc = *(const float4*)(xl + (size_t)sc * 64 + cb);
  }
  for (; i < end; i += 4) {
    int in = i + 4;
    int sn = 0;
    float4 xn = make_float4(0.f, 0.f, 0.f, 0.f);
    if (in < end) {
      sn = srcs[in];
      xn = *(const float4*)(xl + (size_t)sn * 64 + cb);
    }
    const float4* ep = ea_r + (size_t)i * 4;
    float4 e0 = ep[0], e1 = ep[1], e2 = ep[2], e3 = ep[3];
    float4 v;
    v.x = xc.x + xr4.x; v.y = xc.y + xr4.y;
    v.z = xc.z + xr4.z; v.w = xc.w + xr4.w;
    {
      float4 w0 = weS[0][c4], w1 = weS[1][c4], w2 = weS[2][c4], w3 = weS[3][c4];
      v.x += e0.x * w0.x + e0.y * w1.x + e0.z * w2.x + e0.w * w3.x;
      v.y += e0.x * w0.y + e0.y * w1.y + e0.z * w2.y + e0.w * w3.y;
      v.z += e0.x * w0.z + e0.y * w1.z + e0.z * w2.z + e0.w * w3.z;
      v.w += e0.x * w0.w + e0.y * w1.w + e0.z * w2.w + e0.w * w3.w;
    }
    {
      float4 w0 = weS[4][c4], w1 = weS[5][c4], w2 = weS[6][c4], w3 = weS[7][c4];
      v.x += e1.x * w0.x + e1.y * w1.x + e1.z * w2.x + e1.w * w3.x;
      v.y += e1.x * w0.y + e1.y * w1.y + e1.z * w2.y + e1.w * w3.y;
      v.z += e1.x * w0.z + e1.y * w1.z + e1.z * w2.z + e1.w * w3.z;
      v.w += e1.x * w0.w + e1.y * w1.w + e1.z * w2.w + e1.w * w3.w;
    }
    {
      float4 w0 = weS[8][c4], w1 = weS[9][c4], w2 = weS[10][c4], w3 = weS[11][c4];
      v.x += e2.x * w0.x + e2.y * w1.x + e2.z * w2.x + e2.w * w3.x;
      v.y += e2.x * w0.y + e2.y * w1.y + e2.z * w2.y + e2.w * w3.y;
      v.z += e2.x * w0.z + e2.y * w1.z + e2.z * w2.z + e2.w * w3.z;
      v.w += e2.x * w0.w + e2.y * w1.w + e2.z * w2.w + e2.w * w3.w;
    }
    {
      float4 w0 = weS[12][c4], w1 = weS[13][c4], w2 = weS[14][c4], w3 = weS[15][c4];
      v.x += e3.x * w0.x + e3.y * w1.x + e3.z * w2.x + e3.w * w3.x;
      v.y += e3.x * w0.y + e3.y * w1.y + e3.z * w2.y + e3.w * w3.y;
      v.z += e3.x * w0.z + e3.y * w1.z + e3.z * w2.z + e3.w * w3.z;
      v.w += e3.x * w0.w + e3.y * w1.w + e3.z * w2.w + e3.w * w3.w;
    }
    v.x = (v.x > 0.f) ? v.x : 0.2f * v.x;
    v.y = (v.y > 0.f) ? v.y : 0.2f * v.y;
    v.z = (v.z > 0.f) ? v.z : 0.2f * v.z;
    v.w = (v.w > 0.f) ? v.w : 0.2f * v.w;
    float s = at.x * v.x + at.y * v.y + at.z * v.z + at.w * v.w;
#pragma unroll
    for (int off = 8; off >= 1; off >>= 1) s += __shfl_xor(s, off);
    float m_new = fmaxf(m, s);
    float f = __expf(m - m_new);
    float a = __expf(s - m_new);
    denom = denom * f + a;
    acc.x = acc.x * f + a * xc.x; acc.y = acc.y * f + a * xc.y;
    acc.z = acc.z * f + a * xc.z; acc.w = acc.w * f + a * xc.w;
    m = m_new;
    sc = sn; xc = xn;
  }

  // merge 4 subgroups (butterfly over lane bits 4,5)
#pragma unroll
  for (int off = 16; off <= 32; off <<= 1) {
    float mo = __shfl_xor(m, off);
    float dn = __shfl_xor(denom, off);
    float ax = __shfl_xor(acc.x, off), ay = __shfl_xor(acc.y, off);
    float az = __shfl_xor(acc.z, off), aw = __shfl_xor(acc.w, off);
    float M = fmaxf(m, mo);
    float f1 = __expf(m - M), f2 = __expf(mo - M);
    denom = denom * f1 + dn * f2;
    acc.x = acc.x * f1 + ax * f2; acc.y = acc.y * f1 + ay * f2;
    acc.z = acc.z * f1 + az * f2; acc.w = acc.w * f1 + aw * f2;
    m = M;
  }

  if (lane < 16) {
    bool has = (end > beg);
    float4 b4 = *(const float4*)(bias + cb);
    float4 o;
    o.x = (has ? acc.x / denom : 0.f) + b4.x;
    o.y = (has ? acc.y / denom : 0.f) + b4.y;
    o.z = (has ? acc.z / denom : 0.f) + b4.z;
    o.w = (has ? acc.w / denom : 0.f) + b4.w;
    *(float4*)(out + (size_t)n * 64 + cb) = o;
  }
}

// ---------------- launch ----------------

extern "C" void kernel_launch(void* const* d_in, const int* in_sizes, int n_in,
                              void* d_out, int out_size, void* d_ws, size_t ws_size,
                              hipStream_t stream) {
  const float* x    = (const float*)d_in[0];
  const int*   ei   = (const int*)  d_in[1];
  const float* eatt = (const float*)d_in[2];
  const float* Wl1  = (const float*)d_in[3];
  const float* Wr1  = (const float*)d_in[4];
  const float* We1  = (const float*)d_in[5];
  const float* att1 = (const float*)d_in[6];
  const float* b1   = (const float*)d_in[7];
  const float* Wl2  = (const float*)d_in[8];
  const float* Wr2  = (const float*)d_in[9];
  const float* We2  = (const float*)d_in[10];
  const float* att2 = (const float*)d_in[11];
  const float* b2   = (const float*)d_in[12];
  float* out = (float*)d_out;

  char* wsb = (char*)d_ws;
  size_t off = 0;
  auto alloc = [&](size_t bytes) {
    char* p = wsb + off;
    off += (bytes + 255) & ~(size_t)255;
    return p;
  };
  int* counts   = (int*)alloc((size_t)NN * 4);
  int* tmp      = (int*)alloc((size_t)NN * 4);
  int* bsum     = (int*)alloc(32 * 4);
  int* row_ptr  = (int*)alloc((size_t)(NN + 1) * 4);
  int* cursor   = (int*)alloc((size_t)NN * 4);
  int* srcs     = (int*)alloc((size_t)NE * 4);
  float4* ea_r  = (float4*)alloc((size_t)NE * 16 * 4);
  float* xl1    = (float*)alloc((size_t)NN * 256 * 4);
  float* reg2   = (float*)alloc((size_t)NN * 256 * 4);  // xr1; reused for xl2/xr2
  float* hbuf   = (float*)alloc((size_t)NN * 256 * 4);
  float* xr1 = reg2;
  float* xl2 = reg2;                       // xr1 dead after layer 1
  float* xr2 = reg2 + (size_t)NN * 64;

  // CSR by destination (+ src list + edge_attr reorder)
  zero_i32<<<(NN + 255) / 256, 256, 0, stream>>>(counts, NN);
  count_dst<<<(NE + 255) / 256, 256, 0, stream>>>(ei, counts);
  scan_local<<<(NN + 1023) / 1024, 1024, 0, stream>>>(counts, tmp, bsum);
  scan_bsum<<<1, 64, 0, stream>>>(bsum, (NN + 1023) / 1024);
  scan_finish<<<(NN + 255) / 256, 256, 0, stream>>>(counts, tmp, bsum, row_ptr, cursor);
  scatter_edges<<<(NE + 255) / 256, 256, 0, stream>>>(ei, (const float4*)eatt, cursor, srcs, ea_r);

  // layer 1
  gemm_dual_g<128, 256, 16, 1><<<NN / 16, 256, 0, stream>>>(x, Wl1, Wr1, xl1, xr1);
  attn_agg1<<<NN, 256, 0, stream>>>(srcs, row_ptr, ea_r, xl1, xr1, We1, att1, b1, hbuf);

  // layer 2
  gemm_dual_g<256, 64, 8, 4><<<NN / 32, 256, 0, stream>>>(hbuf, Wl2, Wr2, xl2, xr2);
  attn_agg2<<<NN / 4, 256, 0, stream>>>(srcs, row_ptr, ea_r, xl2, xr2, We2, att2, b2, out);
}

// Round 7
// 459.022 us; speedup vs baseline: 1.0551x; 1.0551x over previous
//
#include <hip/hip_runtime.h>

#define NN 20000
#define NE 320000

// ---------------- CSR construction ----------------

__global__ void zero_i32(int* __restrict__ p, int n) {
  int i = blockIdx.x * blockDim.x + threadIdx.x;
  if (i < n) p[i] = 0;
}

__global__ void count_dst(const int* __restrict__ ei, int* __restrict__ counts) {
  int e = blockIdx.x * blockDim.x + threadIdx.x;
  if (e < NE) atomicAdd(&counts[ei[NE + e]], 1);
}

__global__ void scan_local(const int* __restrict__ counts, int* __restrict__ tmp,
                           int* __restrict__ bsum) {
  __shared__ int sh[1024];
  int b = blockIdx.x, t = threadIdx.x, i = b * 1024 + t;
  int v = (i < NN) ? counts[i] : 0;
  sh[t] = v;
  __syncthreads();
  for (int off = 1; off < 1024; off <<= 1) {
    int add = (t >= off) ? sh[t - off] : 0;
    __syncthreads();
    sh[t] += add;
    __syncthreads();
  }
  if (i < NN) tmp[i] = sh[t];
  if (t == 1023) bsum[b] = sh[t];
}

__global__ void scan_bsum(int* __restrict__ bsum, int nb) {
  if (threadIdx.x == 0) {
    int run = 0;
    for (int j = 0; j < nb; ++j) { int v = bsum[j]; bsum[j] = run; run += v; }
  }
}

__global__ void scan_finish(const int* __restrict__ counts, const int* __restrict__ tmp,
                            const int* __restrict__ bsum, int* __restrict__ row_ptr,
                            int* __restrict__ cursor) {
  int i = blockIdx.x * 256 + threadIdx.x;
  if (i == 0) row_ptr[0] = 0;
  if (i < NN) {
    int incl = tmp[i] + bsum[i >> 10];
    row_ptr[i + 1] = incl;
    cursor[i] = incl - counts[i];
  }
}

// scatter: src id, dst id, and edge_attr reordered into CSR position order.
__global__ void scatter_edges(const int* __restrict__ ei, const float4* __restrict__ eattr4,
                              int* __restrict__ cursor, int* __restrict__ srcs,
                              int* __restrict__ dsts, float4* __restrict__ ea_r) {
  int e = blockIdx.x * blockDim.x + threadIdx.x;
  if (e < NE) {
    int d = ei[NE + e];
    int pos = atomicAdd(&cursor[d], 1);
    srcs[pos] = ei[e];
    dsts[pos] = d;
    float4 a0 = eattr4[(size_t)e * 4 + 0];
    float4 a1 = eattr4[(size_t)e * 4 + 1];
    float4 a2 = eattr4[(size_t)e * 4 + 2];
    float4 a3 = eattr4[(size_t)e * 4 + 3];
    ea_r[(size_t)pos * 4 + 0] = a0;
    ea_r[(size_t)pos * 4 + 1] = a1;
    ea_r[(size_t)pos * 4 + 2] = a2;
    ea_r[(size_t)pos * 4 + 3] = a3;
  }
}

// ---------------- dual projection GEMM ----------------

template<int K, int NC, int TMG, int G>
__global__ void gemm_dual_g(const float* __restrict__ A, const float* __restrict__ W1,
                            const float* __restrict__ W2, float* __restrict__ C1,
                            float* __restrict__ C2) {
  constexpr int TM = TMG * G;
  __shared__ float As[TM * K];
  int t = threadIdx.x;
  int n = t & (NC - 1);
  int g = t / NC;
  int m0 = blockIdx.x * TM;
  const float4* A4 = (const float4*)(A + (size_t)m0 * K);
  float4* As4 = (float4*)As;
  for (int idx = t; idx < TM * K / 4; idx += NC * G) As4[idx] = A4[idx];
  __syncthreads();
  float acc1[TMG], acc2[TMG];
#pragma unroll
  for (int m = 0; m < TMG; ++m) { acc1[m] = 0.f; acc2[m] = 0.f; }
  for (int k = 0; k < K; k += 4) {
    float w10 = W1[(k + 0) * NC + n], w11 = W1[(k + 1) * NC + n];
    float w12 = W1[(k + 2) * NC + n], w13 = W1[(k + 3) * NC + n];
    float w20 = W2[(k + 0) * NC + n], w21 = W2[(k + 1) * NC + n];
    float w22 = W2[(k + 2) * NC + n], w23 = W2[(k + 3) * NC + n];
#pragma unroll
    for (int m = 0; m < TMG; ++m) {
      float4 a = *(const float4*)&As[(g * TMG + m) * K + k];
      acc1[m] += a.x * w10 + a.y * w11 + a.z * w12 + a.w * w13;
      acc2[m] += a.x * w20 + a.y * w21 + a.z * w22 + a.w * w23;
    }
  }
#pragma unroll
  for (int m = 0; m < TMG; ++m) {
    size_t row = m0 + g * TMG + m;
    C1[row * NC + n] = acc1[m];
    C2[row * NC + n] = acc2[m];
  }
}

// ---------------- helpers (inline functions, NOT macros: round-6 lesson) ----------------

__device__ __forceinline__ void ea_fma(float4& v, const float4 ea, const float4* w) {
  v.x += ea.x * w[0].x + ea.y * w[1].x + ea.z * w[2].x + ea.w * w[3].x;
  v.y += ea.x * w[0].y + ea.y * w[1].y + ea.z * w[2].y + ea.w * w[3].y;
  v.z += ea.x * w[0].z + ea.y * w[1].z + ea.z * w[2].z + ea.w * w[3].z;
  v.w += ea.x * w[0].w + ea.y * w[1].w + ea.z * w[2].w + ea.w * w[3].w;
}

__device__ __forceinline__ void leaky4(float4& v) {
  v.x = (v.x > 0.f) ? v.x : 0.2f * v.x;
  v.y = (v.y > 0.f) ? v.y : 0.2f * v.y;
  v.z = (v.z > 0.f) ? v.z : 0.2f * v.z;
  v.w = (v.w > 0.f) ? v.w : 0.2f * v.w;
}

// online-softmax update: state (m,d,acc) <- edge (logit l, row vec)
__device__ __forceinline__ void upd4(float& m, float& d, float4& a, float l, const float4 v) {
  float mn = fmaxf(m, l), f = __expf(m - mn), p = __expf(l - mn);
  d = d * f + p;
  a.x = a.x * f + p * v.x; a.y = a.y * f + p * v.y;
  a.z = a.z * f + p * v.z; a.w = a.w * f + p * v.w;
  m = mn;
}

__device__ __forceinline__ void mrg4(float& m, float& d, float4& a, float m2, float d2,
                                     const float4 a2) {
  float M = fmaxf(m, m2), f1 = __expf(m - M), f2 = __expf(m2 - M);
  d = d * f1 + d2 * f2;
  a.x = a.x * f1 + a2.x * f2; a.y = a.y * f1 + a2.y * f2;
  a.z = a.z * f1 + a2.z * f2; a.w = a.w * f1 + a2.w * f2;
  m = M;
}

__device__ __forceinline__ void upd1(float& m, float& d, float& a, float l, float v) {
  float mn = fmaxf(m, l), f = __expf(m - mn), p = __expf(l - mn);
  d = d * f + p; a = a * f + p * v; m = mn;
}

__device__ __forceinline__ void mrg1(float& m, float& d, float& a, float m2, float d2,
                                     float a2) {
  float M = fmaxf(m, m2), f1 = __expf(m - M), f2 = __expf(m2 - M);
  d = d * f1 + d2 * f2; a = a * f1 + a2 * f2; m = M;
}

// ---------------- pass 1: edge logits (pure streaming, weights in regs) ----------------
// layer 1: one wave owns 16 consecutive CSR positions; lane = (head, 4-ch group);
// a wave covers all 4 heads x 64 ch of one edge; 2-edge unroll for load overlap.

__global__ __launch_bounds__(256, 1) void edge_logits1(
    const int* __restrict__ srcs, const int* __restrict__ dsts,
    const float4* __restrict__ ea_r, const float* __restrict__ xl,
    const float* __restrict__ xr, const float* __restrict__ We,
    const float* __restrict__ att, float* __restrict__ logits) {
  int gw = (blockIdx.x * 256 + threadIdx.x) >> 6;  // wave id in [0, NE/16)
  int lane = threadIdx.x & 63;
  int col = (lane >> 4) * 64 + (lane & 15) * 4;
  int h = lane >> 4;
  bool leader = (lane & 15) == 0;
  float4 we[16];
#pragma unroll
  for (int k = 0; k < 16; ++k) we[k] = *(const float4*)(We + k * 256 + col);
  float4 at = *(const float4*)(att + col);
  int base = gw * 16;
  for (int i = base; i < base + 16; i += 2) {
    int s0 = srcs[i], s1 = srcs[i + 1];
    int d0 = dsts[i], d1 = dsts[i + 1];
    float4 xa = *(const float4*)(xl + (size_t)s0 * 256 + col);
    float4 xb = *(const float4*)(xl + (size_t)s1 * 256 + col);
    float4 ra = *(const float4*)(xr + (size_t)d0 * 256 + col);
    float4 rb = *(const float4*)(xr + (size_t)d1 * 256 + col);
    const float4* ep = ea_r + (size_t)i * 4;
    float4 p0 = ep[0], p1 = ep[1], p2 = ep[2], p3 = ep[3];
    float4 q0 = ep[4], q1 = ep[5], q2 = ep[6], q3 = ep[7];
    float4 v0, v1;
    v0.x = xa.x + ra.x; v0.y = xa.y + ra.y; v0.z = xa.z + ra.z; v0.w = xa.w + ra.w;
    v1.x = xb.x + rb.x; v1.y = xb.y + rb.y; v1.z = xb.z + rb.z; v1.w = xb.w + rb.w;
    ea_fma(v0, p0, we + 0); ea_fma(v0, p1, we + 4);
    ea_fma(v0, p2, we + 8); ea_fma(v0, p3, we + 12);
    ea_fma(v1, q0, we + 0); ea_fma(v1, q1, we + 4);
    ea_fma(v1, q2, we + 8); ea_fma(v1, q3, we + 12);
    leaky4(v0); leaky4(v1);
    float sA = at.x * v0.x + at.y * v0.y + at.z * v0.z + at.w * v0.w;
    float sB = at.x * v1.x + at.y * v1.y + at.z * v1.z + at.w * v1.w;
#pragma unroll
    for (int off = 8; off >= 1; off >>= 1) {
      sA += __shfl_xor(sA, off);
      sB += __shfl_xor(sB, off);
    }
    if (leader) {
      logits[4 * i + h] = sA;
      logits[4 * (i + 1) + h] = sB;
    }
  }
}

// layer 2 (H=1, C=64): 16-lane group per edge, 4 edges per wave per iteration.
__global__ __launch_bounds__(256, 1) void edge_logits2(
    const int* __restrict__ srcs, const int* __restrict__ dsts,
    const float4* __restrict__ ea_r, const float* __restrict__ xl,
    const float* __restrict__ xr, const float* __restrict__ We,
    const float* __restrict__ att, float* __restrict__ logits) {
  int gw = (blockIdx.x * 256 + threadIdx.x) >> 6;  // wave id in [0, NE/32)
  int lane = threadIdx.x & 63;
  int g = lane >> 4, q = lane & 15;
  int cb = q * 4;
  float4 we[16];
#pragma unroll
  for (int k = 0; k < 16; ++k) we[k] = *(const float4*)(We + k * 64 + cb);
  float4 at = *(const float4*)(att + cb);
  int base = gw * 32;
  for (int it = 0; it < 8; ++it) {
    int i = base + it * 4 + g;
    int s = srcs[i], d = dsts[i];
    float4 xa = *(const float4*)(xl + (size_t)s * 64 + cb);
    float4 ra = *(const float4*)(xr + (size_t)d * 64 + cb);
    const float4* ep = ea_r + (size_t)i * 4;
    float4 p0 = ep[0], p1 = ep[1], p2 = ep[2], p3 = ep[3];
    float4 v;
    v.x = xa.x + ra.x; v.y = xa.y + ra.y; v.z = xa.z + ra.z; v.w = xa.w + ra.w;
    ea_fma(v, p0, we + 0); ea_fma(v, p1, we + 4);
    ea_fma(v, p2, we + 8); ea_fma(v, p3, we + 12);
    leaky4(v);
    float s_ = at.x * v.x + at.y * v.y + at.z * v.z + at.w * v.w;
#pragma unroll
    for (int off = 8; off >= 1; off >>= 1) s_ += __shfl_xor(s_, off);
    if (q == 0) logits[i] = s_;
  }
}

// ---------------- pass 2: thin aggregation (4 independent edge streams/wave) ----------------

__global__ __launch_bounds__(256) void aggregate1(
    const int* __restrict__ srcs, const int* __restrict__ row_ptr,
    const float* __restrict__ logits, const float* __restrict__ xl,
    const float* __restrict__ bias, float* __restrict__ hout) {
  int w = threadIdx.x >> 6, lane = threadIdx.x & 63;
  int n = blockIdx.x * 4 + w;
  int col = (lane >> 4) * 64 + (lane & 15) * 4;
  int h = lane >> 4;
  int beg = row_ptr[n], end = row_ptr[n + 1];
  float m0 = -1e30f, m1 = -1e30f, m2 = -1e30f, m3 = -1e30f;
  float d0 = 0.f, d1 = 0.f, d2 = 0.f, d3 = 0.f;
  float4 a0 = {0, 0, 0, 0}, a1 = {0, 0, 0, 0}, a2 = {0, 0, 0, 0}, a3 = {0, 0, 0, 0};
  int i = beg;
  for (; i + 4 <= end; i += 4) {
    int s0 = srcs[i], s1 = srcs[i + 1], s2 = srcs[i + 2], s3 = srcs[i + 3];
    float l0 = logits[4 * i + h];
    float l1 = logits[4 * (i + 1) + h];
    float l2 = logits[4 * (i + 2) + h];
    float l3 = logits[4 * (i + 3) + h];
    float4 x0 = *(const float4*)(xl + (size_t)s0 * 256 + col);
    float4 x1 = *(const float4*)(xl + (size_t)s1 * 256 + col);
    float4 x2 = *(const float4*)(xl + (size_t)s2 * 256 + col);
    float4 x3 = *(const float4*)(xl + (size_t)s3 * 256 + col);
    upd4(m0, d0, a0, l0, x0);
    upd4(m1, d1, a1, l1, x1);
    upd4(m2, d2, a2, l2, x2);
    upd4(m3, d3, a3, l3, x3);
  }
  for (; i < end; ++i) {
    int s0 = srcs[i];
    float l0 = logits[4 * i + h];
    float4 x0 = *(const float4*)(xl + (size_t)s0 * 256 + col);
    upd4(m0, d0, a0, l0, x0);
  }
  mrg4(m0, d0, a0, m1, d1, a1);
  mrg4(m2, d2, a2, m3, d3, a3);
  mrg4(m0, d0, a0, m2, d2, a2);
  bool has = end > beg;
  float rd = has ? 1.f / d0 : 0.f;
  float4 b4 = *(const float4*)(bias + col);
  float4 o;
  o.x = a0.x * rd + b4.x;
  o.y = a0.y * rd + b4.y;
  o.z = a0.z * rd + b4.z;
  o.w = a0.w * rd + b4.w;
  o.x = (o.x > 0.f) ? o.x : (__expf(o.x) - 1.f);
  o.y = (o.y > 0.f) ? o.y : (__expf(o.y) - 1.f);
  o.z = (o.z > 0.f) ? o.z : (__expf(o.z) - 1.f);
  o.w = (o.w > 0.f) ? o.w : (__expf(o.w) - 1.f);
  *(float4*)(hout + (size_t)n * 256 + col) = o;
}

// layer 2: wave per node; lane = channel (64); scalar accumulators.
__global__ __launch_bounds__(256) void aggregate2(
    const int* __restrict__ srcs, const int* __restrict__ row_ptr,
    const float* __restrict__ logits, const float* __restrict__ xl,
    const float* __restrict__ bias, float* __restrict__ out) {
  int w = threadIdx.x >> 6, lane = threadIdx.x & 63;
  int n = blockIdx.x * 4 + w;
  int beg = row_ptr[n], end = row_ptr[n + 1];
  float m0 = -1e30f, m1 = -1e30f, m2 = -1e30f, m3 = -1e30f;
  float d0 = 0.f, d1 = 0.f, d2 = 0.f, d3 = 0.f;
  float a0 = 0.f, a1 = 0.f, a2 = 0.f, a3 = 0.f;
  int i = beg;
  for (; i + 4 <= end; i += 4) {
    int s0 = srcs[i], s1 = srcs[i + 1], s2 = srcs[i + 2], s3 = srcs[i + 3];
    float l0 = logits[i], l1 = logits[i + 1], l2 = logits[i + 2], l3 = logits[i + 3];
    float x0 = xl[(size_t)s0 * 64 + lane];
    float x1 = xl[(size_t)s1 * 64 + lane];
    float x2 = xl[(size_t)s2 * 64 + lane];
    float x3 = xl[(size_t)s3 * 64 + lane];
    upd1(m0, d0, a0, l0, x0);
    upd1(m1, d1, a1, l1, x1);
    upd1(m2, d2, a2, l2, x2);
    upd1(m3, d3, a3, l3, x3);
  }
  for (; i < end; ++i) {
    int s0 = srcs[i];
    float l0 = logits[i];
    float x0 = xl[(size_t)s0 * 64 + lane];
    upd1(m0, d0, a0, l0, x0);
  }
  mrg1(m0, d0, a0, m1, d1, a1);
  mrg1(m2, d2, a2, m3, d3, a3);
  mrg1(m0, d0, a0, m2, d2, a2);
  bool has = end > beg;
  float o = (has ? a0 / d0 : 0.f) + bias[lane];
  out[(size_t)n * 64 + lane] = o;
}

// ---------------- launch ----------------

extern "C" void kernel_launch(void* const* d_in, const int* in_sizes, int n_in,
                              void* d_out, int out_size, void* d_ws, size_t ws_size,
                              hipStream_t stream) {
  const float* x    = (const float*)d_in[0];
  const int*   ei   = (const int*)  d_in[1];
  const float* eatt = (const float*)d_in[2];
  const float* Wl1  = (const float*)d_in[3];
  const float* Wr1  = (const float*)d_in[4];
  const float* We1  = (const float*)d_in[5];
  const float* att1 = (const float*)d_in[6];
  const float* b1   = (const float*)d_in[7];
  const float* Wl2  = (const float*)d_in[8];
  const float* Wr2  = (const float*)d_in[9];
  const float* We2  = (const float*)d_in[10];
  const float* att2 = (const float*)d_in[11];
  const float* b2   = (const float*)d_in[12];
  float* out = (float*)d_out;

  char* wsb = (char*)d_ws;
  size_t off = 0;
  auto alloc = [&](size_t bytes) {
    char* p = wsb + off;
    off += (bytes + 255) & ~(size_t)255;
    return p;
  };
  int* counts    = (int*)alloc((size_t)NN * 4);
  int* tmp       = (int*)alloc((size_t)NN * 4);
  int* bsum      = (int*)alloc(32 * 4);
  int* row_ptr   = (int*)alloc((size_t)(NN + 1) * 4);
  int* cursor    = (int*)alloc((size_t)NN * 4);
  int* srcs      = (int*)alloc((size_t)NE * 4);
  int* dsts      = (int*)alloc((size_t)NE * 4);
  float4* ea_r   = (float4*)alloc((size_t)NE * 16 * 4);
  float* logits1 = (float*)alloc((size_t)NE * 4 * 4);
  float* xl1     = (float*)alloc((size_t)NN * 256 * 4);
  float* reg2    = (float*)alloc((size_t)NN * 256 * 4);  // xr1; reused xl2/xr2
  float* hbuf    = (float*)alloc((size_t)NN * 256 * 4);
  float* xr1 = reg2;
  float* xl2 = reg2;                        // xr1 dead after layer 1
  float* xr2 = reg2 + (size_t)NN * 64;
  float* logits2 = logits1;                 // logits1 dead after aggregate1

  // CSR by destination (+ srcs/dsts + edge_attr reorder)
  zero_i32<<<(NN + 255) / 256, 256, 0, stream>>>(counts, NN);
  count_dst<<<(NE + 255) / 256, 256, 0, stream>>>(ei, counts);
  scan_local<<<(NN + 1023) / 1024, 1024, 0, stream>>>(counts, tmp, bsum);
  scan_bsum<<<1, 64, 0, stream>>>(bsum, (NN + 1023) / 1024);
  scan_finish<<<(NN + 255) / 256, 256, 0, stream>>>(counts, tmp, bsum, row_ptr, cursor);
  scatter_edges<<<(NE + 255) / 256, 256, 0, stream>>>(ei, (const float4*)eatt, cursor,
                                                      srcs, dsts, ea_r);

  // layer 1
  gemm_dual_g<128, 256, 16, 1><<<NN / 16, 256, 0, stream>>>(x, Wl1, Wr1, xl1, xr1);
  edge_logits1<<<NE / 16 / 4, 256, 0, stream>>>(srcs, dsts, ea_r, xl1, xr1, We1, att1, logits1);
  aggregate1<<<NN / 4, 256, 0, stream>>>(srcs, row_ptr, logits1, xl1, b1, hbuf);

  // layer 2
  gemm_dual_g<256, 64, 8, 4><<<NN / 32, 256, 0, stream>>>(hbuf, Wl2, Wr2, xl2, xr2);
  edge_logits2<<<NE / 32 / 4, 256, 0, stream>>>(srcs, dsts, ea_r, xl2, xr2, We2, att2, logits2);
  aggregate2<<<NN / 4, 256, 0, stream>>>(srcs, row_ptr, logits2, xl2, b2, out);
}

// Round 9
// 396.190 us; speedup vs baseline: 1.2225x; 1.1586x over previous
//
#include <hip/hip_runtime.h>

#define NN 20000
#define NE 320000

typedef __attribute__((ext_vector_type(8))) short bf16x8;
typedef __attribute__((ext_vector_type(4))) float f32x4;

__device__ __forceinline__ float bf2f(unsigned short u) {
  union { unsigned int i; float f; } v; v.i = ((unsigned int)u) << 16; return v.f;
}
__device__ __forceinline__ unsigned short f2bf(float f) {
  union { float f; unsigned int i; } v; v.f = f;
  unsigned int r = v.i + 0x7FFF + ((v.i >> 16) & 1);
  return (unsigned short)(r >> 16);
}

// ---------------- CSR construction ----------------

__global__ void zero_i32(int* __restrict__ p, int n) {
  int i = blockIdx.x * blockDim.x + threadIdx.x;
  if (i < n) p[i] = 0;
}

__global__ void count_dst(const int* __restrict__ ei, int* __restrict__ counts) {
  int e = blockIdx.x * blockDim.x + threadIdx.x;
  if (e < NE) atomicAdd(&counts[ei[NE + e]], 1);
}

__global__ void scan_local(const int* __restrict__ counts, int* __restrict__ tmp,
                           int* __restrict__ bsum) {
  __shared__ int sh[1024];
  int b = blockIdx.x, t = threadIdx.x, i = b * 1024 + t;
  int v = (i < NN) ? counts[i] : 0;
  sh[t] = v;
  __syncthreads();
  for (int off = 1; off < 1024; off <<= 1) {
    int add = (t >= off) ? sh[t - off] : 0;
    __syncthreads();
    sh[t] += add;
    __syncthreads();
  }
  if (i < NN) tmp[i] = sh[t];
  if (t == 1023) bsum[b] = sh[t];
}

__global__ void scan_bsum(int* __restrict__ bsum, int nb) {
  if (threadIdx.x == 0) {
    int run = 0;
    for (int j = 0; j < nb; ++j) { int v = bsum[j]; bsum[j] = run; run += v; }
  }
}

__global__ void scan_finish(const int* __restrict__ counts, const int* __restrict__ tmp,
                            const int* __restrict__ bsum, int* __restrict__ row_ptr,
                            int* __restrict__ cursor) {
  int i = blockIdx.x * 256 + threadIdx.x;
  if (i == 0) row_ptr[0] = 0;
  if (i < NN) {
    int incl = tmp[i] + bsum[i >> 10];
    row_ptr[i + 1] = incl;
    cursor[i] = incl - counts[i];
  }
}

__global__ void scatter_edges(const int* __restrict__ ei, const float4* __restrict__ eattr4,
                              int* __restrict__ cursor, int* __restrict__ srcs,
                              int* __restrict__ dsts, float4* __restrict__ ea_r) {
  int e = blockIdx.x * blockDim.x + threadIdx.x;
  if (e < NE) {
    int d = ei[NE + e];
    int pos = atomicAdd(&cursor[d], 1);
    srcs[pos] = ei[e];
    dsts[pos] = d;
    float4 a0 = eattr4[(size_t)e * 4 + 0];
    float4 a1 = eattr4[(size_t)e * 4 + 1];
    float4 a2 = eattr4[(size_t)e * 4 + 2];
    float4 a3 = eattr4[(size_t)e * 4 + 3];
    ea_r[(size_t)pos * 4 + 0] = a0;
    ea_r[(size_t)pos * 4 + 1] = a1;
    ea_r[(size_t)pos * 4 + 2] = a2;
    ea_r[(size_t)pos * 4 + 3] = a3;
  }
}

// ---------------- split-bf16 conversion (hi + lo, ~fp32 fidelity) ----------------

__global__ void split_bf16(const float* __restrict__ src, unsigned short* __restrict__ hi,
                           unsigned short* __restrict__ lo, int n) {
  int i = blockIdx.x * 256 + threadIdx.x;
  if (i < n) {
    float v = src[i];
    unsigned short h = f2bf(v);
    hi[i] = h;
    lo[i] = f2bf(v - bf2f(h));
  }
}

// concat two [K][N0] fp32 matrices into one [K][2*N0], split into hi/lo bf16
__global__ void cat_split_bf16(const float* __restrict__ W1, const float* __restrict__ W2,
                               unsigned short* __restrict__ hi, unsigned short* __restrict__ lo,
                               int N0, int total) {
  int i = blockIdx.x * 256 + threadIdx.x;
  if (i < total) {
    int n2 = 2 * N0;
    int n = i % n2, k = i / n2;
    float v = (n < N0) ? W1[k * N0 + n] : W2[k * N0 + n - N0];
    unsigned short h = f2bf(v);
    hi[i] = h;
    lo[i] = f2bf(v - bf2f(h));
  }
}

// ---------------- split-bf16 MFMA GEMM: C(fp32) = A @ B, A,B given as hi/lo ----------------
// tile 64x64, 4 waves; layouts verified in round 8 (error was pure quantization):
// A-frag A[m=lane&15][k=quad*8+j], B-frag B[k=quad*8+j][n=lane&15], C col=lane&15,row=quad*4+r.
// acc = Ah*Bh + Ah*Bl + Al*Bh  (error ~2^-17, MFMA is cheap — GEMM is staging-bound)

template<int K>
__global__ __launch_bounds__(256) void mfma_gemm_split(
    const unsigned short* __restrict__ Ah, const unsigned short* __restrict__ Al,
    const unsigned short* __restrict__ Bh, const unsigned short* __restrict__ Bl,
    float* __restrict__ C, int M, int N) {
  constexpr int AP = 40;  // padded LDS row: stride 20 banks -> 2-way alias (free)
  __shared__ unsigned short Ash[64 * AP], Asl[64 * AP];
  __shared__ unsigned short Bsh[64 * AP], Bsl[64 * AP];
  int t = threadIdx.x;
  int wv = t >> 6, lane = t & 63;
  int quad = lane >> 4, mrow = lane & 15;
  int m0 = blockIdx.x * 64;
  int n0 = blockIdx.y * 64;
  f32x4 acc[4];
#pragma unroll
  for (int i = 0; i < 4; ++i) acc[i] = (f32x4){0.f, 0.f, 0.f, 0.f};

  for (int ks = 0; ks < K; ks += 32) {
    __syncthreads();
    {  // stage A hi+lo: thread t -> row t/4, 8 bf16 at (t%4)*8
      int row = t >> 2, seg = (t & 3) * 8;
      int gr = m0 + row;
      ushort4 h0 = {0, 0, 0, 0}, h1 = {0, 0, 0, 0}, l0 = {0, 0, 0, 0}, l1 = {0, 0, 0, 0};
      if (gr < M) {
        const ushort4* sh4 = (const ushort4*)(Ah + (size_t)gr * K + ks + seg);
        const ushort4* sl4 = (const ushort4*)(Al + (size_t)gr * K + ks + seg);
        h0 = sh4[0]; h1 = sh4[1];
        l0 = sl4[0]; l1 = sl4[1];
      }
      unsigned short* dh = Ash + row * AP + seg;
      unsigned short* dl = Asl + row * AP + seg;
      *(ushort4*)dh = h0; *(ushort4*)(dh + 4) = h1;
      *(ushort4*)dl = l0; *(ushort4*)(dl + 4) = l1;
    }
    {  // stage B hi+lo transposed: thread t -> k-row t/8, 8 cols at (t%8)*8
      int krow = t >> 3, noff = (t & 7) * 8;
      const unsigned short* sh = Bh + (size_t)(ks + krow) * N + n0 + noff;
      const unsigned short* sl = Bl + (size_t)(ks + krow) * N + n0 + noff;
      ushort4 h0 = *(const ushort4*)sh, h1 = *(const ushort4*)(sh + 4);
      ushort4 l0 = *(const ushort4*)sl, l1 = *(const ushort4*)(sl + 4);
      unsigned short hv[8] = {h0.x, h0.y, h0.z, h0.w, h1.x, h1.y, h1.z, h1.w};
      unsigned short lv[8] = {l0.x, l0.y, l0.z, l0.w, l1.x, l1.y, l1.z, l1.w};
#pragma unroll
      for (int j = 0; j < 8; ++j) {
        Bsh[(noff + j) * AP + krow] = hv[j];
        Bsl[(noff + j) * AP + krow] = lv[j];
      }
    }
    __syncthreads();
    bf16x8 ah = *(const bf16x8*)(Ash + (wv * 16 + mrow) * AP + quad * 8);
    bf16x8 al = *(const bf16x8*)(Asl + (wv * 16 + mrow) * AP + quad * 8);
#pragma unroll
    for (int nt = 0; nt < 4; ++nt) {
      bf16x8 bh = *(const bf16x8*)(Bsh + (nt * 16 + mrow) * AP + quad * 8);
      bf16x8 bl = *(const bf16x8*)(Bsl + (nt * 16 + mrow) * AP + quad * 8);
      acc[nt] = __builtin_amdgcn_mfma_f32_16x16x32_bf16(ah, bh, acc[nt], 0, 0, 0);
      acc[nt] = __builtin_amdgcn_mfma_f32_16x16x32_bf16(ah, bl, acc[nt], 0, 0, 0);
      acc[nt] = __builtin_amdgcn_mfma_f32_16x16x32_bf16(al, bh, acc[nt], 0, 0, 0);
    }
  }
#pragma unroll
  for (int nt = 0; nt < 4; ++nt)
#pragma unroll
    for (int r = 0; r < 4; ++r) {
      int row = m0 + wv * 16 + quad * 4 + r;
      if (row < M) C[(size_t)row * N + n0 + nt * 16 + mrow] = acc[nt][r];
    }
}

// ---------------- helpers ----------------

__device__ __forceinline__ void ea_fma(float4& v, const float4 ea, const float4* w) {
  v.x += ea.x * w[0].x + ea.y * w[1].x + ea.z * w[2].x + ea.w * w[3].x;
  v.y += ea.x * w[0].y + ea.y * w[1].y + ea.z * w[2].y + ea.w * w[3].y;
  v.z += ea.x * w[0].z + ea.y * w[1].z + ea.z * w[2].z + ea.w * w[3].z;
  v.w += ea.x * w[0].w + ea.y * w[1].w + ea.z * w[2].w + ea.w * w[3].w;
}

__device__ __forceinline__ void leaky4(float4& v) {
  v.x = (v.x > 0.f) ? v.x : 0.2f * v.x;
  v.y = (v.y > 0.f) ? v.y : 0.2f * v.y;
  v.z = (v.z > 0.f) ? v.z : 0.2f * v.z;
  v.w = (v.w > 0.f) ? v.w : 0.2f * v.w;
}

__device__ __forceinline__ void upd4(float& m, float& d, float4& a, float l, const float4 v) {
  float mn = fmaxf(m, l), f = __expf(m - mn), p = __expf(l - mn);
  d = d * f + p;
  a.x = a.x * f + p * v.x; a.y = a.y * f + p * v.y;
  a.z = a.z * f + p * v.z; a.w = a.w * f + p * v.w;
  m = mn;
}

__device__ __forceinline__ void mrg4(float& m, float& d, float4& a, float m2, float d2,
                                     const float4 a2) {
  float M = fmaxf(m, m2), f1 = __expf(m - M), f2 = __expf(m2 - M);
  d = d * f1 + d2 * f2;
  a.x = a.x * f1 + a2.x * f2; a.y = a.y * f1 + a2.y * f2;
  a.z = a.z * f1 + a2.z * f2; a.w = a.w * f1 + a2.w * f2;
  m = M;
}

__device__ __forceinline__ void upd1(float& m, float& d, float& a, float l, float v) {
  float mn = fmaxf(m, l), f = __expf(m - mn), p = __expf(l - mn);
  d = d * f + p; a = a * f + p * v; m = mn;
}

__device__ __forceinline__ void mrg1(float& m, float& d, float& a, float m2, float d2,
                                     float a2) {
  float M = fmaxf(m, m2), f1 = __expf(m - M), f2 = __expf(m2 - M);
  d = d * f1 + d2 * f2; a = a * f1 + a2 * f2; m = M;
}

// ---------------- pass 1: edge logits (fp32 gathers — round-7 verified) ----------------

__global__ __launch_bounds__(256, 1) void edge_logits1(
    const int* __restrict__ srcs, const int* __restrict__ dsts,
    const float4* __restrict__ ea_r, const float* __restrict__ xl,
    const float* __restrict__ xr, const float* __restrict__ We,
    const float* __restrict__ att, float* __restrict__ logits) {
  int gw = (blockIdx.x * 256 + threadIdx.x) >> 6;
  int lane = threadIdx.x & 63;
  int col = (lane >> 4) * 64 + (lane & 15) * 4;
  int h = lane >> 4;
  bool leader = (lane & 15) == 0;
  float4 we[16];
#pragma unroll
  for (int k = 0; k < 16; ++k) we[k] = *(const float4*)(We + k * 256 + col);
  float4 at = *(const float4*)(att + col);
  int base = gw * 16;
  for (int i = base; i < base + 16; i += 2) {
    int s0 = srcs[i], s1 = srcs[i + 1];
    int d0 = dsts[i], d1 = dsts[i + 1];
    float4 xa = *(const float4*)(xl + (size_t)s0 * 512 + col);
    float4 xb = *(const float4*)(xl + (size_t)s1 * 512 + col);
    float4 ra = *(const float4*)(xr + (size_t)d0 * 512 + col);
    float4 rb = *(const float4*)(xr + (size_t)d1 * 512 + col);
    const float4* ep = ea_r + (size_t)i * 4;
    float4 p0 = ep[0], p1 = ep[1], p2 = ep[2], p3 = ep[3];
    float4 q0 = ep[4], q1 = ep[5], q2 = ep[6], q3 = ep[7];
    float4 v0, v1;
    v0.x = xa.x + ra.x; v0.y = xa.y + ra.y; v0.z = xa.z + ra.z; v0.w = xa.w + ra.w;
    v1.x = xb.x + rb.x; v1.y = xb.y + rb.y; v1.z = xb.z + rb.z; v1.w = xb.w + rb.w;
    ea_fma(v0, p0, we + 0); ea_fma(v0, p1, we + 4);
    ea_fma(v0, p2, we + 8); ea_fma(v0, p3, we + 12);
    ea_fma(v1, q0, we + 0); ea_fma(v1, q1, we + 4);
    ea_fma(v1, q2, we + 8); ea_fma(v1, q3, we + 12);
    leaky4(v0); leaky4(v1);
    float sA = at.x * v0.x + at.y * v0.y + at.z * v0.z + at.w * v0.w;
    float sB = at.x * v1.x + at.y * v1.y + at.z * v1.z + at.w * v1.w;
#pragma unroll
    for (int off = 8; off >= 1; off >>= 1) {
      sA += __shfl_xor(sA, off);
      sB += __shfl_xor(sB, off);
    }
    if (leader) {
      logits[4 * i + h] = sA;
      logits[4 * (i + 1) + h] = sB;
    }
  }
}

__global__ __launch_bounds__(256, 1) void edge_logits2(
    const int* __restrict__ srcs, const int* __restrict__ dsts,
    const float4* __restrict__ ea_r, const float* __restrict__ xl,
    const float* __restrict__ xr, const float* __restrict__ We,
    const float* __restrict__ att, float* __restrict__ logits) {
  int gw = (blockIdx.x * 256 + threadIdx.x) >> 6;
  int lane = threadIdx.x & 63;
  int g = lane >> 4, q = lane & 15;
  int cb = q * 4;
  float4 we[16];
#pragma unroll
  for (int k = 0; k < 16; ++k) we[k] = *(const float4*)(We + k * 64 + cb);
  float4 at = *(const float4*)(att + cb);
  int base = gw * 32;
  for (int it = 0; it < 8; ++it) {
    int i = base + it * 4 + g;
    int s = srcs[i], d = dsts[i];
    float4 xa = *(const float4*)(xl + (size_t)s * 128 + cb);
    float4 ra = *(const float4*)(xr + (size_t)d * 128 + cb);
    const float4* ep = ea_r + (size_t)i * 4;
    float4 p0 = ep[0], p1 = ep[1], p2 = ep[2], p3 = ep[3];
    float4 v;
    v.x = xa.x + ra.x; v.y = xa.y + ra.y; v.z = xa.z + ra.z; v.w = xa.w + ra.w;
    ea_fma(v, p0, we + 0); ea_fma(v, p1, we + 4);
    ea_fma(v, p2, we + 8); ea_fma(v, p3, we + 12);
    leaky4(v);
    float s_ = at.x * v.x + at.y * v.y + at.z * v.z + at.w * v.w;
#pragma unroll
    for (int off = 8; off >= 1; off >>= 1) s_ += __shfl_xor(s_, off);
    if (q == 0) logits[i] = s_;
  }
}

// ---------------- pass 2: thin aggregation ----------------
// layer 1: fp32 gathers; emits h as split hi/lo bf16 (GEMM-2 A input, ~fp32 fidelity).

__global__ __launch_bounds__(256) void aggregate1(
    const int* __restrict__ srcs, const int* __restrict__ row_ptr,
    const float* __restrict__ logits, const float* __restrict__ xl,
    const float* __restrict__ bias, unsigned short* __restrict__ h_hi,
    unsigned short* __restrict__ h_lo) {
  int w = threadIdx.x >> 6, lane = threadIdx.x & 63;
  int n = blockIdx.x * 4 + w;
  int col = (lane >> 4) * 64 + (lane & 15) * 4;
  int h = lane >> 4;
  int beg = row_ptr[n], end = row_ptr[n + 1];
  float m0 = -1e30f, m1 = -1e30f, m2 = -1e30f, m3 = -1e30f;
  float d0 = 0.f, d1 = 0.f, d2 = 0.f, d3 = 0.f;
  float4 a0 = {0, 0, 0, 0}, a1 = {0, 0, 0, 0}, a2 = {0, 0, 0, 0}, a3 = {0, 0, 0, 0};
  int i = beg;
  for (; i + 4 <= end; i += 4) {
    int s0 = srcs[i], s1 = srcs[i + 1], s2 = srcs[i + 2], s3 = srcs[i + 3];
    float l0 = logits[4 * i + h];
    float l1 = logits[4 * (i + 1) + h];
    float l2 = logits[4 * (i + 2) + h];
    float l3 = logits[4 * (i + 3) + h];
    float4 x0 = *(const float4*)(xl + (size_t)s0 * 512 + col);
    float4 x1 = *(const float4*)(xl + (size_t)s1 * 512 + col);
    float4 x2 = *(const float4*)(xl + (size_t)s2 * 512 + col);
    float4 x3 = *(const float4*)(xl + (size_t)s3 * 512 + col);
    upd4(m0, d0, a0, l0, x0);
    upd4(m1, d1, a1, l1, x1);
    upd4(m2, d2, a2, l2, x2);
    upd4(m3, d3, a3, l3, x3);
  }
  for (; i < end; ++i) {
    int s0 = srcs[i];
    float l0 = logits[4 * i + h];
    float4 x0 = *(const float4*)(xl + (size_t)s0 * 512 + col);
    upd4(m0, d0, a0, l0, x0);
  }
  mrg4(m0, d0, a0, m1, d1, a1);
  mrg4(m2, d2, a2, m3, d3, a3);
  mrg4(m0, d0, a0, m2, d2, a2);
  bool has = end > beg;
  float rd = has ? 1.f / d0 : 0.f;
  float4 b4 = *(const float4*)(bias + col);
  float4 o;
  o.x = a0.x * rd + b4.x;
  o.y = a0.y * rd + b4.y;
  o.z = a0.z * rd + b4.z;
  o.w = a0.w * rd + b4.w;
  o.x = (o.x > 0.f) ? o.x : (__expf(o.x) - 1.f);
  o.y = (o.y > 0.f) ? o.y : (__expf(o.y) - 1.f);
  o.z = (o.z > 0.f) ? o.z : (__expf(o.z) - 1.f);
  o.w = (o.w > 0.f) ? o.w : (__expf(o.w) - 1.f);
  ushort4 oh, ol;
  oh.x = f2bf(o.x); ol.x = f2bf(o.x - bf2f(oh.x));
  oh.y = f2bf(o.y); ol.y = f2bf(o.y - bf2f(oh.y));
  oh.z = f2bf(o.z); ol.z = f2bf(o.z - bf2f(oh.z));
  oh.w = f2bf(o.w); ol.w = f2bf(o.w - bf2f(oh.w));
  *(ushort4*)(h_hi + (size_t)n * 256 + col) = oh;
  *(ushort4*)(h_lo + (size_t)n * 256 + col) = ol;
}

// layer 2: fp32 gathers, fp32 output.
__global__ __launch_bounds__(256) void aggregate2(
    const int* __restrict__ srcs, const int* __restrict__ row_ptr,
    const float* __restrict__ logits, const float* __restrict__ xl,
    const float* __restrict__ bias, float* __restrict__ out) {
  int w = threadIdx.x >> 6, lane = threadIdx.x & 63;
  int n = blockIdx.x * 4 + w;
  int beg = row_ptr[n], end = row_ptr[n + 1];
  float m0 = -1e30f, m1 = -1e30f, m2 = -1e30f, m3 = -1e30f;
  float d0 = 0.f, d1 = 0.f, d2 = 0.f, d3 = 0.f;
  float a0 = 0.f, a1 = 0.f, a2 = 0.f, a3 = 0.f;
  int i = beg;
  for (; i + 4 <= end; i += 4) {
    int s0 = srcs[i], s1 = srcs[i + 1], s2 = srcs[i + 2], s3 = srcs[i + 3];
    float l0 = logits[i], l1 = logits[i + 1], l2 = logits[i + 2], l3 = logits[i + 3];
    float x0 = xl[(size_t)s0 * 128 + lane];
    float x1 = xl[(size_t)s1 * 128 + lane];
    float x2 = xl[(size_t)s2 * 128 + lane];
    float x3 = xl[(size_t)s3 * 128 + lane];
    upd1(m0, d0, a0, l0, x0);
    upd1(m1, d1, a1, l1, x1);
    upd1(m2, d2, a2, l2, x2);
    upd1(m3, d3, a3, l3, x3);
  }
  for (; i < end; ++i) {
    int s0 = srcs[i];
    float l0 = logits[i];
    float x0 = xl[(size_t)s0 * 128 + lane];
    upd1(m0, d0, a0, l0, x0);
  }
  mrg1(m0, d0, a0, m1, d1, a1);
  mrg1(m2, d2, a2, m3, d3, a3);
  mrg1(m0, d0, a0, m2, d2, a2);
  bool has = end > beg;
  float o = (has ? a0 / d0 : 0.f) + bias[lane];
  out[(size_t)n * 64 + lane] = o;
}

// ---------------- launch ----------------

extern "C" void kernel_launch(void* const* d_in, const int* in_sizes, int n_in,
                              void* d_out, int out_size, void* d_ws, size_t ws_size,
                              hipStream_t stream) {
  const float* x    = (const float*)d_in[0];
  const int*   ei   = (const int*)  d_in[1];
  const float* eatt = (const float*)d_in[2];
  const float* Wl1  = (const float*)d_in[3];
  const float* Wr1  = (const float*)d_in[4];
  const float* We1  = (const float*)d_in[5];
  const float* att1 = (const float*)d_in[6];
  const float* b1   = (const float*)d_in[7];
  const float* Wl2  = (const float*)d_in[8];
  const float* Wr2  = (const float*)d_in[9];
  const float* We2  = (const float*)d_in[10];
  const float* att2 = (const float*)d_in[11];
  const float* b2   = (const float*)d_in[12];
  float* out = (float*)d_out;

  char* wsb = (char*)d_ws;
  size_t off = 0;
  auto alloc = [&](size_t bytes) {
    char* p = wsb + off;
    off += (bytes + 255) & ~(size_t)255;
    return p;
  };
  int* counts    = (int*)alloc((size_t)NN * 4);
  int* tmp       = (int*)alloc((size_t)NN * 4);
  int* bsum      = (int*)alloc(32 * 4);
  int* row_ptr   = (int*)alloc((size_t)(NN + 1) * 4);
  int* cursor    = (int*)alloc((size_t)NN * 4);
  int* srcs      = (int*)alloc((size_t)NE * 4);
  int* dsts      = (int*)alloc((size_t)NE * 4);
  float4* ea_r   = (float4*)alloc((size_t)NE * 16 * 4);
  float* logits1 = (float*)alloc((size_t)NE * 4 * 4);
  unsigned short* x_hi  = (unsigned short*)alloc((size_t)NN * 128 * 2);
  unsigned short* x_lo  = (unsigned short*)alloc((size_t)NN * 128 * 2);
  unsigned short* W1h   = (unsigned short*)alloc((size_t)128 * 512 * 2);
  unsigned short* W1l   = (unsigned short*)alloc((size_t)128 * 512 * 2);
  unsigned short* W2h   = (unsigned short*)alloc((size_t)256 * 128 * 2);
  unsigned short* W2l   = (unsigned short*)alloc((size_t)256 * 128 * 2);
  unsigned short* h_hi  = (unsigned short*)alloc((size_t)NN * 256 * 2);
  unsigned short* h_lo  = (unsigned short*)alloc((size_t)NN * 256 * 2);
  float* xlr1    = (float*)alloc((size_t)NN * 512 * 4);
  float* xlr2    = xlr1;          // alias: xlr1 dead after aggregate1
  float* logits2 = logits1;       // alias: logits1 dead after aggregate1

  // CSR by destination (+ srcs/dsts + edge_attr reorder)
  zero_i32<<<(NN + 255) / 256, 256, 0, stream>>>(counts, NN);
  count_dst<<<(NE + 255) / 256, 256, 0, stream>>>(ei, counts);
  scan_local<<<(NN + 1023) / 1024, 1024, 0, stream>>>(counts, tmp, bsum);
  scan_bsum<<<1, 64, 0, stream>>>(bsum, (NN + 1023) / 1024);
  scan_finish<<<(NN + 255) / 256, 256, 0, stream>>>(counts, tmp, bsum, row_ptr, cursor);
  scatter_edges<<<(NE + 255) / 256, 256, 0, stream>>>(ei, (const float4*)eatt, cursor,
                                                      srcs, dsts, ea_r);

  // split-bf16 conversions
  split_bf16<<<(NN * 128 + 255) / 256, 256, 0, stream>>>(x, x_hi, x_lo, NN * 128);
  cat_split_bf16<<<(128 * 512 + 255) / 256, 256, 0, stream>>>(Wl1, Wr1, W1h, W1l, 256, 128 * 512);
  cat_split_bf16<<<(256 * 128 + 255) / 256, 256, 0, stream>>>(Wl2, Wr2, W2h, W2l, 64, 256 * 128);

  // layer 1
  mfma_gemm_split<128><<<dim3((NN + 63) / 64, 8), 256, 0, stream>>>(
      x_hi, x_lo, W1h, W1l, xlr1, NN, 512);
  edge_logits1<<<NE / 16 / 4, 256, 0, stream>>>(srcs, dsts, ea_r, xlr1, xlr1 + 256,
                                                We1, att1, logits1);
  aggregate1<<<NN / 4, 256, 0, stream>>>(srcs, row_ptr, logits1, xlr1, b1, h_hi, h_lo);

  // layer 2
  mfma_gemm_split<256><<<dim3((NN + 63) / 64, 2), 256, 0, stream>>>(
      h_hi, h_lo, W2h, W2l, xlr2, NN, 128);
  edge_logits2<<<NE / 32 / 4, 256, 0, stream>>>(srcs, dsts, ea_r, xlr2, xlr2 + 64,
                                                We2, att2, logits2);
  aggregate2<<<NN / 4, 256, 0, stream>>>(srcs, row_ptr, logits2, xlr2, b2, out);
}

// Round 10
// 386.522 us; speedup vs baseline: 1.2530x; 1.0250x over previous
//
#include <hip/hip_runtime.h>

#define NN 20000
#define NE 320000

typedef __attribute__((ext_vector_type(8))) short bf16x8;
typedef __attribute__((ext_vector_type(4))) float f32x4;

__device__ __forceinline__ float bf2f(unsigned short u) {
  union { unsigned int i; float f; } v; v.i = ((unsigned int)u) << 16; return v.f;
}
__device__ __forceinline__ unsigned short f2bf(float f) {
  union { float f; unsigned int i; } v; v.f = f;
  unsigned int r = v.i + 0x7FFF + ((v.i >> 16) & 1);
  return (unsigned short)(r >> 16);
}

// ---------------- CSR construction ----------------

__global__ void zero_i32(int* __restrict__ p, int n) {
  int i = blockIdx.x * blockDim.x + threadIdx.x;
  if (i < n) p[i] = 0;
}

__global__ void count_dst(const int* __restrict__ ei, int* __restrict__ counts) {
  int e = blockIdx.x * blockDim.x + threadIdx.x;
  if (e < NE) atomicAdd(&counts[ei[NE + e]], 1);
}

__global__ void scan_local(const int* __restrict__ counts, int* __restrict__ tmp,
                           int* __restrict__ bsum) {
  __shared__ int sh[1024];
  int b = blockIdx.x, t = threadIdx.x, i = b * 1024 + t;
  int v = (i < NN) ? counts[i] : 0;
  sh[t] = v;
  __syncthreads();
  for (int off = 1; off < 1024; off <<= 1) {
    int add = (t >= off) ? sh[t - off] : 0;
    __syncthreads();
    sh[t] += add;
    __syncthreads();
  }
  if (i < NN) tmp[i] = sh[t];
  if (t == 1023) bsum[b] = sh[t];
}

__global__ void scan_bsum(int* __restrict__ bsum, int nb) {
  if (threadIdx.x == 0) {
    int run = 0;
    for (int j = 0; j < nb; ++j) { int v = bsum[j]; bsum[j] = run; run += v; }
  }
}

__global__ void scan_finish(const int* __restrict__ counts, const int* __restrict__ tmp,
                            const int* __restrict__ bsum, int* __restrict__ row_ptr,
                            int* __restrict__ cursor) {
  int i = blockIdx.x * 256 + threadIdx.x;
  if (i == 0) row_ptr[0] = 0;
  if (i < NN) {
    int incl = tmp[i] + bsum[i >> 10];
    row_ptr[i + 1] = incl;
    cursor[i] = incl - counts[i];
  }
}

__global__ void scatter_edges(const int* __restrict__ ei, const float4* __restrict__ eattr4,
                              int* __restrict__ cursor, int* __restrict__ srcs,
                              float4* __restrict__ ea_r) {
  int e = blockIdx.x * blockDim.x + threadIdx.x;
  if (e < NE) {
    int d = ei[NE + e];
    int pos = atomicAdd(&cursor[d], 1);
    srcs[pos] = ei[e];
    float4 a0 = eattr4[(size_t)e * 4 + 0];
    float4 a1 = eattr4[(size_t)e * 4 + 1];
    float4 a2 = eattr4[(size_t)e * 4 + 2];
    float4 a3 = eattr4[(size_t)e * 4 + 3];
    ea_r[(size_t)pos * 4 + 0] = a0;
    ea_r[(size_t)pos * 4 + 1] = a1;
    ea_r[(size_t)pos * 4 + 2] = a2;
    ea_r[(size_t)pos * 4 + 3] = a3;
  }
}

// ---------------- split-bf16 conversion ----------------

__global__ void split_bf16(const float* __restrict__ src, unsigned short* __restrict__ hi,
                           unsigned short* __restrict__ lo, int n) {
  int i = blockIdx.x * 256 + threadIdx.x;
  if (i < n) {
    float v = src[i];
    unsigned short h = f2bf(v);
    hi[i] = h;
    lo[i] = f2bf(v - bf2f(h));
  }
}

// concat two [K][N0] fp32 matrices over columns and store TRANSPOSED [N][K] hi/lo bf16
__global__ void cat_split_T(const float* __restrict__ W1, const float* __restrict__ W2,
                            unsigned short* __restrict__ hi, unsigned short* __restrict__ lo,
                            int N0, int K, int total) {
  int i = blockIdx.x * 256 + threadIdx.x;
  if (i < total) {
    int n = i / K, k = i - n * K;
    float v = (n < N0) ? W1[k * N0 + n] : W2[k * N0 + n - N0];
    unsigned short h = f2bf(v);
    hi[i] = h;
    lo[i] = f2bf(v - bf2f(h));
  }
}

// ---------------- split-bf16 MFMA GEMM, B-resident-in-LDS ----------------
// C(fp32)[M][N] = A[M][K] @ B[K][N]; Bt given as [N][K] hi/lo. Block = 4 waves,
// tile 64x64. B staged ONCE (vector copies); A-frags loaded directly from
// global each K-step — no __syncthreads / DS writes in the K-loop (round-9
// lesson: the per-K-step transpose scatter serialized the DS pipe).
// acc = Ah*Bh + Ah*Bl + Al*Bh (~fp32 fidelity; verified round 9).

template<int K>
__global__ __launch_bounds__(256) void mfma_gemm_B(
    const unsigned short* __restrict__ Ah, const unsigned short* __restrict__ Al,
    const unsigned short* __restrict__ Bth, const unsigned short* __restrict__ Btl,
    float* __restrict__ C, int M, int N) {
  constexpr int BP = K + 24;  // shorts: rows 16B-aligned, bank advance 12 -> 2-way (free)
  __shared__ unsigned short Bsh[64 * BP], Bsl[64 * BP];
  int t = threadIdx.x;
  int wv = t >> 6, lane = t & 63;
  int quad = lane >> 4, mrow = lane & 15;
  int m0 = blockIdx.x * 64;
  int n0 = blockIdx.y * 64;

  for (int idx = t; idx < 64 * K / 8; idx += 256) {
    int n = idx / (K / 8), seg = (idx - n * (K / 8)) * 8;
    *(uint4*)(Bsh + n * BP + seg) = *(const uint4*)(Bth + (size_t)(n0 + n) * K + seg);
    *(uint4*)(Bsl + n * BP + seg) = *(const uint4*)(Btl + (size_t)(n0 + n) * K + seg);
  }
  __syncthreads();

  f32x4 acc[4];
#pragma unroll
  for (int i = 0; i < 4; ++i) acc[i] = (f32x4){0.f, 0.f, 0.f, 0.f};

  int arow = m0 + wv * 16 + mrow;
  if (arow >= M) arow = M - 1;  // clamp; stores are guarded
  const unsigned short* ap_h = Ah + (size_t)arow * K + quad * 8;
  const unsigned short* ap_l = Al + (size_t)arow * K + quad * 8;

  for (int ks = 0; ks < K; ks += 32) {
    bf16x8 ah = *(const bf16x8*)(ap_h + ks);
    bf16x8 al = *(const bf16x8*)(ap_l + ks);
#pragma unroll
    for (int nt = 0; nt < 4; ++nt) {
      bf16x8 bh = *(const bf16x8*)(Bsh + (nt * 16 + mrow) * BP + ks + quad * 8);
      bf16x8 bl = *(const bf16x8*)(Bsl + (nt * 16 + mrow) * BP + ks + quad * 8);
      acc[nt] = __builtin_amdgcn_mfma_f32_16x16x32_bf16(ah, bh, acc[nt], 0, 0, 0);
      acc[nt] = __builtin_amdgcn_mfma_f32_16x16x32_bf16(ah, bl, acc[nt], 0, 0, 0);
      acc[nt] = __builtin_amdgcn_mfma_f32_16x16x32_bf16(al, bh, acc[nt], 0, 0, 0);
    }
  }
#pragma unroll
  for (int nt = 0; nt < 4; ++nt)
#pragma unroll
    for (int r = 0; r < 4; ++r) {
      int row = m0 + wv * 16 + quad * 4 + r;
      if (row < M) C[(size_t)row * N + n0 + nt * 16 + mrow] = acc[nt][r];
    }
}

// ---------------- helpers ----------------

__device__ __forceinline__ void ea_fma(float4& v, const float4 ea, const float4* w) {
  v.x += ea.x * w[0].x + ea.y * w[1].x + ea.z * w[2].x + ea.w * w[3].x;
  v.y += ea.x * w[0].y + ea.y * w[1].y + ea.z * w[2].y + ea.w * w[3].y;
  v.z += ea.x * w[0].z + ea.y * w[1].z + ea.z * w[2].z + ea.w * w[3].z;
  v.w += ea.x * w[0].w + ea.y * w[1].w + ea.z * w[2].w + ea.w * w[3].w;
}

__device__ __forceinline__ void leaky4(float4& v) {
  v.x = (v.x > 0.f) ? v.x : 0.2f * v.x;
  v.y = (v.y > 0.f) ? v.y : 0.2f * v.y;
  v.z = (v.z > 0.f) ? v.z : 0.2f * v.z;
  v.w = (v.w > 0.f) ? v.w : 0.2f * v.w;
}

__device__ __forceinline__ void upd4(float& m, float& d, float4& a, float l, const float4 v) {
  float mn = fmaxf(m, l), f = __expf(m - mn), p = __expf(l - mn);
  d = d * f + p;
  a.x = a.x * f + p * v.x; a.y = a.y * f + p * v.y;
  a.z = a.z * f + p * v.z; a.w = a.w * f + p * v.w;
  m = mn;
}

__device__ __forceinline__ void mrg4(float& m, float& d, float4& a, float m2, float d2,
                                     const float4 a2) {
  float M = fmaxf(m, m2), f1 = __expf(m - M), f2 = __expf(m2 - M);
  d = d * f1 + d2 * f2;
  a.x = a.x * f1 + a2.x * f2; a.y = a.y * f1 + a2.y * f2;
  a.z = a.z * f1 + a2.z * f2; a.w = a.w * f1 + a2.w * f2;
  m = M;
}

__device__ __forceinline__ void upd1(float& m, float& d, float& a, float l, float v) {
  float mn = fmaxf(m, l), f = __expf(m - mn), p = __expf(l - mn);
  d = d * f + p; a = a * f + p * v; m = mn;
}

__device__ __forceinline__ void mrg1(float& m, float& d, float& a, float m2, float d2,
                                     float a2) {
  float M = fmaxf(m, m2), f1 = __expf(m - M), f2 = __expf(m2 - M);
  d = d * f1 + d2 * f2; a = a * f1 + a2 * f2; m = M;
}

// ---------------- pass 1: edge logits, PER-NODE (xr loaded once per node) ----------------

__global__ __launch_bounds__(256, 1) void edge_logits1(
    const int* __restrict__ srcs, const int* __restrict__ row_ptr,
    const float4* __restrict__ ea_r, const float* __restrict__ xl,
    const float* __restrict__ xr, const float* __restrict__ We,
    const float* __restrict__ att, float* __restrict__ logits) {
  int w = threadIdx.x >> 6, lane = threadIdx.x & 63;
  int n = blockIdx.x * 4 + w;
  int col = (lane >> 4) * 64 + (lane & 15) * 4;
  int h = lane >> 4;
  bool leader = (lane & 15) == 0;
  float4 we[16];
#pragma unroll
  for (int k = 0; k < 16; ++k) we[k] = *(const float4*)(We + k * 256 + col);
  float4 at = *(const float4*)(att + col);
  float4 xr4 = *(const float4*)(xr + (size_t)n * 512 + col);
  int beg = row_ptr[n], end = row_ptr[n + 1];

  int i = beg;
  for (; i + 2 <= end; i += 2) {
    int s0 = srcs[i], s1 = srcs[i + 1];
    float4 xa = *(const float4*)(xl + (size_t)s0 * 512 + col);
    float4 xb = *(const float4*)(xl + (size_t)s1 * 512 + col);
    const float4* ep = ea_r + (size_t)i * 4;
    float4 p0 = ep[0], p1 = ep[1], p2 = ep[2], p3 = ep[3];
    float4 q0 = ep[4], q1 = ep[5], q2 = ep[6], q3 = ep[7];
    float4 v0, v1;
    v0.x = xa.x + xr4.x; v0.y = xa.y + xr4.y; v0.z = xa.z + xr4.z; v0.w = xa.w + xr4.w;
    v1.x = xb.x + xr4.x; v1.y = xb.y + xr4.y; v1.z = xb.z + xr4.z; v1.w = xb.w + xr4.w;
    ea_fma(v0, p0, we + 0); ea_fma(v0, p1, we + 4);
    ea_fma(v0, p2, we + 8); ea_fma(v0, p3, we + 12);
    ea_fma(v1, q0, we + 0); ea_fma(v1, q1, we + 4);
    ea_fma(v1, q2, we + 8); ea_fma(v1, q3, we + 12);
    leaky4(v0); leaky4(v1);
    float sA = at.x * v0.x + at.y * v0.y + at.z * v0.z + at.w * v0.w;
    float sB = at.x * v1.x + at.y * v1.y + at.z * v1.z + at.w * v1.w;
#pragma unroll
    for (int off = 8; off >= 1; off >>= 1) {
      sA += __shfl_xor(sA, off);
      sB += __shfl_xor(sB, off);
    }
    if (leader) {
      logits[4 * i + h] = sA;
      logits[4 * (i + 1) + h] = sB;
    }
  }
  if (i < end) {
    int s0 = srcs[i];
    float4 xa = *(const float4*)(xl + (size_t)s0 * 512 + col);
    const float4* ep = ea_r + (size_t)i * 4;
    float4 p0 = ep[0], p1 = ep[1], p2 = ep[2], p3 = ep[3];
    float4 v0;
    v0.x = xa.x + xr4.x; v0.y = xa.y + xr4.y; v0.z = xa.z + xr4.z; v0.w = xa.w + xr4.w;
    ea_fma(v0, p0, we + 0); ea_fma(v0, p1, we + 4);
    ea_fma(v0, p2, we + 8); ea_fma(v0, p3, we + 12);
    leaky4(v0);
    float sA = at.x * v0.x + at.y * v0.y + at.z * v0.z + at.w * v0.w;
#pragma unroll
    for (int off = 8; off >= 1; off >>= 1) sA += __shfl_xor(sA, off);
    if (leader) logits[4 * i + h] = sA;
  }
}

// layer 2 (H=1): wave per node; 4 subgroups of 16 lanes take every 4th edge.
__global__ __launch_bounds__(256, 1) void edge_logits2(
    const int* __restrict__ srcs, const int* __restrict__ row_ptr,
    const float4* __restrict__ ea_r, const float* __restrict__ xl,
    const float* __restrict__ xr, const float* __restrict__ We,
    const float* __restrict__ att, float* __restrict__ logits) {
  int w = threadIdx.x >> 6, lane = threadIdx.x & 63;
  int n = blockIdx.x * 4 + w;
  int g = lane >> 4, q = lane & 15;
  int cb = q * 4;
  float4 we[16];
#pragma unroll
  for (int k = 0; k < 16; ++k) we[k] = *(const float4*)(We + k * 64 + cb);
  float4 at = *(const float4*)(att + cb);
  float4 xr4 = *(const float4*)(xr + (size_t)n * 128 + cb);
  int beg = row_ptr[n], end = row_ptr[n + 1];
  for (int i = beg + g; i < end; i += 4) {
    int s = srcs[i];
    float4 xa = *(const float4*)(xl + (size_t)s * 128 + cb);
    const float4* ep = ea_r + (size_t)i * 4;
    float4 p0 = ep[0], p1 = ep[1], p2 = ep[2], p3 = ep[3];
    float4 v;
    v.x = xa.x + xr4.x; v.y = xa.y + xr4.y; v.z = xa.z + xr4.z; v.w = xa.w + xr4.w;
    ea_fma(v, p0, we + 0); ea_fma(v, p1, we + 4);
    ea_fma(v, p2, we + 8); ea_fma(v, p3, we + 12);
    leaky4(v);
    float s_ = at.x * v.x + at.y * v.y + at.z * v.z + at.w * v.w;
#pragma unroll
    for (int off = 8; off >= 1; off >>= 1) s_ += __shfl_xor(s_, off);
    if (q == 0) logits[i] = s_;
  }
}

// ---------------- pass 2: thin aggregation (round-7 verified) ----------------

__global__ __launch_bounds__(256) void aggregate1(
    const int* __restrict__ srcs, const int* __restrict__ row_ptr,
    const float* __restrict__ logits, const float* __restrict__ xl,
    const float* __restrict__ bias, unsigned short* __restrict__ h_hi,
    unsigned short* __restrict__ h_lo) {
  int w = threadIdx.x >> 6, lane = threadIdx.x & 63;
  int n = blockIdx.x * 4 + w;
  int col = (lane >> 4) * 64 + (lane & 15) * 4;
  int h = lane >> 4;
  int beg = row_ptr[n], end = row_ptr[n + 1];
  float m0 = -1e30f, m1 = -1e30f, m2 = -1e30f, m3 = -1e30f;
  float d0 = 0.f, d1 = 0.f, d2 = 0.f, d3 = 0.f;
  float4 a0 = {0, 0, 0, 0}, a1 = {0, 0, 0, 0}, a2 = {0, 0, 0, 0}, a3 = {0, 0, 0, 0};
  int i = beg;
  for (; i + 4 <= end; i += 4) {
    int s0 = srcs[i], s1 = srcs[i + 1], s2 = srcs[i + 2], s3 = srcs[i + 3];
    float l0 = logits[4 * i + h];
    float l1 = logits[4 * (i + 1) + h];
    float l2 = logits[4 * (i + 2) + h];
    float l3 = logits[4 * (i + 3) + h];
    float4 x0 = *(const float4*)(xl + (size_t)s0 * 512 + col);
    float4 x1 = *(const float4*)(xl + (size_t)s1 * 512 + col);
    float4 x2 = *(const float4*)(xl + (size_t)s2 * 512 + col);
    float4 x3 = *(const float4*)(xl + (size_t)s3 * 512 + col);
    upd4(m0, d0, a0, l0, x0);
    upd4(m1, d1, a1, l1, x1);
    upd4(m2, d2, a2, l2, x2);
    upd4(m3, d3, a3, l3, x3);
  }
  for (; i < end; ++i) {
    int s0 = srcs[i];
    float l0 = logits[4 * i + h];
    float4 x0 = *(const float4*)(xl + (size_t)s0 * 512 + col);
    upd4(m0, d0, a0, l0, x0);
  }
  mrg4(m0, d0, a0, m1, d1, a1);
  mrg4(m2, d2, a2, m3, d3, a3);
  mrg4(m0, d0, a0, m2, d2, a2);
  bool has = end > beg;
  float rd = has ? 1.f / d0 : 0.f;
  float4 b4 = *(const float4*)(bias + col);
  float4 o;
  o.x = a0.x * rd + b4.x;
  o.y = a0.y * rd + b4.y;
  o.z = a0.z * rd + b4.z;
  o.w = a0.w * rd + b4.w;
  o.x = (o.x > 0.f) ? o.x : (__expf(o.x) - 1.f);
  o.y = (o.y > 0.f) ? o.y : (__expf(o.y) - 1.f);
  o.z = (o.z > 0.f) ? o.z : (__expf(o.z) - 1.f);
  o.w = (o.w > 0.f) ? o.w : (__expf(o.w) - 1.f);
  ushort4 oh, ol;
  oh.x = f2bf(o.x); ol.x = f2bf(o.x - bf2f(oh.x));
  oh.y = f2bf(o.y); ol.y = f2bf(o.y - bf2f(oh.y));
  oh.z = f2bf(o.z); ol.z = f2bf(o.z - bf2f(oh.z));
  oh.w = f2bf(o.w); ol.w = f2bf(o.w - bf2f(oh.w));
  *(ushort4*)(h_hi + (size_t)n * 256 + col) = oh;
  *(ushort4*)(h_lo + (size_t)n * 256 + col) = ol;
}

__global__ __launch_bounds__(256) void aggregate2(
    const int* __restrict__ srcs, const int* __restrict__ row_ptr,
    const float* __restrict__ logits, const float* __restrict__ xl,
    const float* __restrict__ bias, float* __restrict__ out) {
  int w = threadIdx.x >> 6, lane = threadIdx.x & 63;
  int n = blockIdx.x * 4 + w;
  int beg = row_ptr[n], end = row_ptr[n + 1];
  float m0 = -1e30f, m1 = -1e30f, m2 = -1e30f, m3 = -1e30f;
  float d0 = 0.f, d1 = 0.f, d2 = 0.f, d3 = 0.f;
  float a0 = 0.f, a1 = 0.f, a2 = 0.f, a3 = 0.f;
  int i = beg;
  for (; i + 4 <= end; i += 4) {
    int s0 = srcs[i], s1 = srcs[i + 1], s2 = srcs[i + 2], s3 = srcs[i + 3];
    float l0 = logits[i], l1 = logits[i + 1], l2 = logits[i + 2], l3 = logits[i + 3];
    float x0 = xl[(size_t)s0 * 128 + lane];
    float x1 = xl[(size_t)s1 * 128 + lane];
    float x2 = xl[(size_t)s2 * 128 + lane];
    float x3 = xl[(size_t)s3 * 128 + lane];
    upd1(m0, d0, a0, l0, x0);
    upd1(m1, d1, a1, l1, x1);
    upd1(m2, d2, a2, l2, x2);
    upd1(m3, d3, a3, l3, x3);
  }
  for (; i < end; ++i) {
    int s0 = srcs[i];
    float l0 = logits[i];
    float x0 = xl[(size_t)s0 * 128 + lane];
    upd1(m0, d0, a0, l0, x0);
  }
  mrg1(m0, d0, a0, m1, d1, a1);
  mrg1(m2, d2, a2, m3, d3, a3);
  mrg1(m0, d0, a0, m2, d2, a2);
  bool has = end > beg;
  float o = (has ? a0 / d0 : 0.f) + bias[lane];
  out[(size_t)n * 64 + lane] = o;
}

// ---------------- launch ----------------

extern "C" void kernel_launch(void* const* d_in, const int* in_sizes, int n_in,
                              void* d_out, int out_size, void* d_ws, size_t ws_size,
                              hipStream_t stream) {
  const float* x    = (const float*)d_in[0];
  const int*   ei   = (const int*)  d_in[1];
  const float* eatt = (const float*)d_in[2];
  const float* Wl1  = (const float*)d_in[3];
  const float* Wr1  = (const float*)d_in[4];
  const float* We1  = (const float*)d_in[5];
  const float* att1 = (const float*)d_in[6];
  const float* b1   = (const float*)d_in[7];
  const float* Wl2  = (const float*)d_in[8];
  const float* Wr2  = (const float*)d_in[9];
  const float* We2  = (const float*)d_in[10];
  const float* att2 = (const float*)d_in[11];
  const float* b2   = (const float*)d_in[12];
  float* out = (float*)d_out;

  char* wsb = (char*)d_ws;
  size_t off = 0;
  auto alloc = [&](size_t bytes) {
    char* p = wsb + off;
    off += (bytes + 255) & ~(size_t)255;
    return p;
  };
  int* counts    = (int*)alloc((size_t)NN * 4);
  int* tmp       = (int*)alloc((size_t)NN * 4);
  int* bsum      = (int*)alloc(32 * 4);
  int* row_ptr   = (int*)alloc((size_t)(NN + 1) * 4);
  int* cursor    = (int*)alloc((size_t)NN * 4);
  int* srcs      = (int*)alloc((size_t)NE * 4);
  float4* ea_r   = (float4*)alloc((size_t)NE * 16 * 4);
  float* logits1 = (float*)alloc((size_t)NE * 4 * 4);
  unsigned short* x_hi  = (unsigned short*)alloc((size_t)NN * 128 * 2);
  unsigned short* x_lo  = (unsigned short*)alloc((size_t)NN * 128 * 2);
  unsigned short* W1th  = (unsigned short*)alloc((size_t)512 * 128 * 2);
  unsigned short* W1tl  = (unsigned short*)alloc((size_t)512 * 128 * 2);
  unsigned short* W2th  = (unsigned short*)alloc((size_t)128 * 256 * 2);
  unsigned short* W2tl  = (unsigned short*)alloc((size_t)128 * 256 * 2);
  unsigned short* h_hi  = (unsigned short*)alloc((size_t)NN * 256 * 2);
  unsigned short* h_lo  = (unsigned short*)alloc((size_t)NN * 256 * 2);
  float* xlr1    = (float*)alloc((size_t)NN * 512 * 4);
  float* xlr2    = xlr1;          // alias: xlr1 dead after aggregate1
  float* logits2 = logits1;       // alias: logits1 dead after aggregate1

  // CSR by destination (+ srcs + edge_attr reorder)
  zero_i32<<<(NN + 255) / 256, 256, 0, stream>>>(counts, NN);
  count_dst<<<(NE + 255) / 256, 256, 0, stream>>>(ei, counts);
  scan_local<<<(NN + 1023) / 1024, 1024, 0, stream>>>(counts, tmp, bsum);
  scan_bsum<<<1, 64, 0, stream>>>(bsum, (NN + 1023) / 1024);
  scan_finish<<<(NN + 255) / 256, 256, 0, stream>>>(counts, tmp, bsum, row_ptr, cursor);
  scatter_edges<<<(NE + 255) / 256, 256, 0, stream>>>(ei, (const float4*)eatt, cursor,
                                                      srcs, ea_r);

  // split-bf16 conversions (W transposed for the B-resident GEMM)
  split_bf16<<<(NN * 128 + 255) / 256, 256, 0, stream>>>(x, x_hi, x_lo, NN * 128);
  cat_split_T<<<(512 * 128 + 255) / 256, 256, 0, stream>>>(Wl1, Wr1, W1th, W1tl, 256, 128,
                                                           512 * 128);
  cat_split_T<<<(128 * 256 + 255) / 256, 256, 0, stream>>>(Wl2, Wr2, W2th, W2tl, 64, 256,
                                                           128 * 256);

  // layer 1
  mfma_gemm_B<128><<<dim3((NN + 63) / 64, 8), 256, 0, stream>>>(
      x_hi, x_lo, W1th, W1tl, xlr1, NN, 512);
  edge_logits1<<<NN / 4, 256, 0, stream>>>(srcs, row_ptr, ea_r, xlr1, xlr1 + 256,
                                           We1, att1, logits1);
  aggregate1<<<NN / 4, 256, 0, stream>>>(srcs, row_ptr, logits1, xlr1, b1, h_hi, h_lo);

  // layer 2
  mfma_gemm_B<256><<<dim3((NN + 63) / 64, 2), 256, 0, stream>>>(
      h_hi, h_lo, W2th, W2tl, xlr2, NN, 128);
  edge_logits2<<<NN / 4, 256, 0, stream>>>(srcs, row_ptr, ea_r, xlr2, xlr2 + 64,
                                           We2, att2, logits2);
  aggregate2<<<NN / 4, 256, 0, stream>>>(srcs, row_ptr, logits2, xlr2, b2, out);
}

// Round 11
// 357.572 us; speedup vs baseline: 1.3545x; 1.0810x over previous
//
#include <hip/hip_runtime.h>

#define NN 20000
#define NE 320000

typedef __attribute__((ext_vector_type(8))) short bf16x8;
typedef __attribute__((ext_vector_type(4))) float f32x4;

__device__ __forceinline__ float bf2f(unsigned short u) {
  union { unsigned int i; float f; } v; v.i = ((unsigned int)u) << 16; return v.f;
}
__device__ __forceinline__ unsigned short f2bf(float f) {
  union { float f; unsigned int i; } v; v.f = f;
  unsigned int r = v.i + 0x7FFF + ((v.i >> 16) & 1);
  return (unsigned short)(r >> 16);
}
__device__ __forceinline__ float4 ld_bf4(const unsigned short* p) {
  ushort4 u = *(const ushort4*)p;
  float4 f;
  f.x = bf2f(u.x); f.y = bf2f(u.y); f.z = bf2f(u.z); f.w = bf2f(u.w);
  return f;
}

// ---------------- CSR construction ----------------

__global__ void zero_i32(int* __restrict__ p, int n) {
  int i = blockIdx.x * blockDim.x + threadIdx.x;
  if (i < n) p[i] = 0;
}

__global__ void count_dst(const int* __restrict__ ei, int* __restrict__ counts) {
  int e = blockIdx.x * blockDim.x + threadIdx.x;
  if (e < NE) atomicAdd(&counts[ei[NE + e]], 1);
}

__global__ void scan_local(const int* __restrict__ counts, int* __restrict__ tmp,
                           int* __restrict__ bsum) {
  __shared__ int sh[1024];
  int b = blockIdx.x, t = threadIdx.x, i = b * 1024 + t;
  int v = (i < NN) ? counts[i] : 0;
  sh[t] = v;
  __syncthreads();
  for (int off = 1; off < 1024; off <<= 1) {
    int add = (t >= off) ? sh[t - off] : 0;
    __syncthreads();
    sh[t] += add;
    __syncthreads();
  }
  if (i < NN) tmp[i] = sh[t];
  if (t == 1023) bsum[b] = sh[t];
}

__global__ void scan_bsum(int* __restrict__ bsum, int nb) {
  if (threadIdx.x == 0) {
    int run = 0;
    for (int j = 0; j < nb; ++j) { int v = bsum[j]; bsum[j] = run; run += v; }
  }
}

__global__ void scan_finish(const int* __restrict__ counts, const int* __restrict__ tmp,
                            const int* __restrict__ bsum, int* __restrict__ row_ptr,
                            int* __restrict__ cursor) {
  int i = blockIdx.x * 256 + threadIdx.x;
  if (i == 0) row_ptr[0] = 0;
  if (i < NN) {
    int incl = tmp[i] + bsum[i >> 10];
    row_ptr[i + 1] = incl;
    cursor[i] = incl - counts[i];
  }
}

__global__ void scatter_edges(const int* __restrict__ ei, const float4* __restrict__ eattr4,
                              int* __restrict__ cursor, int* __restrict__ srcs,
                              int* __restrict__ dsts, float4* __restrict__ ea_r) {
  int e = blockIdx.x * blockDim.x + threadIdx.x;
  if (e < NE) {
    int d = ei[NE + e];
    int pos = atomicAdd(&cursor[d], 1);
    srcs[pos] = ei[e];
    dsts[pos] = d;
    float4 a0 = eattr4[(size_t)e * 4 + 0];
    float4 a1 = eattr4[(size_t)e * 4 + 1];
    float4 a2 = eattr4[(size_t)e * 4 + 2];
    float4 a3 = eattr4[(size_t)e * 4 + 3];
    ea_r[(size_t)pos * 4 + 0] = a0;
    ea_r[(size_t)pos * 4 + 1] = a1;
    ea_r[(size_t)pos * 4 + 2] = a2;
    ea_r[(size_t)pos * 4 + 3] = a3;
  }
}

// ---------------- split-bf16 conversion ----------------

__global__ void split_bf16(const float* __restrict__ src, unsigned short* __restrict__ hi,
                           unsigned short* __restrict__ lo, int n) {
  int i = blockIdx.x * 256 + threadIdx.x;
  if (i < n) {
    float v = src[i];
    unsigned short h = f2bf(v);
    hi[i] = h;
    lo[i] = f2bf(v - bf2f(h));
  }
}

// concat two [K][N0] fp32 matrices over columns, store TRANSPOSED [N][K] hi/lo bf16
__global__ void cat_split_T(const float* __restrict__ W1, const float* __restrict__ W2,
                            unsigned short* __restrict__ hi, unsigned short* __restrict__ lo,
                            int N0, int K, int total) {
  int i = blockIdx.x * 256 + threadIdx.x;
  if (i < total) {
    int n = i / K, k = i - n * K;
    float v = (n < N0) ? W1[k * N0 + n] : W2[k * N0 + n - N0];
    unsigned short h = f2bf(v);
    hi[i] = h;
    lo[i] = f2bf(v - bf2f(h));
  }
}

// ---------------- split-bf16 MFMA GEMM, B-resident-in-LDS, hi/lo-plane output ----------------
// acc = Ah*Bh + Ah*Bl + Al*Bh (~fp32); C emitted as hi+lo bf16 planes so the
// gather kernels can read hi-only (8 B/lane) — the round-11 traffic lever.

template<int K>
__global__ __launch_bounds__(256) void mfma_gemm_B(
    const unsigned short* __restrict__ Ah, const unsigned short* __restrict__ Al,
    const unsigned short* __restrict__ Bth, const unsigned short* __restrict__ Btl,
    unsigned short* __restrict__ Ch, unsigned short* __restrict__ Cl, int M, int N) {
  constexpr int BP = K + 24;  // rows 16B-aligned; bank advance 12 -> 2-way alias (free)
  __shared__ unsigned short Bsh[64 * BP], Bsl[64 * BP];
  int t = threadIdx.x;
  int wv = t >> 6, lane = t & 63;
  int quad = lane >> 4, mrow = lane & 15;
  int m0 = blockIdx.x * 64;
  int n0 = blockIdx.y * 64;

  for (int idx = t; idx < 64 * K / 8; idx += 256) {
    int n = idx / (K / 8), seg = (idx - n * (K / 8)) * 8;
    *(uint4*)(Bsh + n * BP + seg) = *(const uint4*)(Bth + (size_t)(n0 + n) * K + seg);
    *(uint4*)(Bsl + n * BP + seg) = *(const uint4*)(Btl + (size_t)(n0 + n) * K + seg);
  }
  __syncthreads();

  f32x4 acc[4];
#pragma unroll
  for (int i = 0; i < 4; ++i) acc[i] = (f32x4){0.f, 0.f, 0.f, 0.f};

  int arow = m0 + wv * 16 + mrow;
  if (arow >= M) arow = M - 1;  // clamp; stores are guarded
  const unsigned short* ap_h = Ah + (size_t)arow * K + quad * 8;
  const unsigned short* ap_l = Al + (size_t)arow * K + quad * 8;

  for (int ks = 0; ks < K; ks += 32) {
    bf16x8 ah = *(const bf16x8*)(ap_h + ks);
    bf16x8 al = *(const bf16x8*)(ap_l + ks);
#pragma unroll
    for (int nt = 0; nt < 4; ++nt) {
      bf16x8 bh = *(const bf16x8*)(Bsh + (nt * 16 + mrow) * BP + ks + quad * 8);
      bf16x8 bl = *(const bf16x8*)(Bsl + (nt * 16 + mrow) * BP + ks + quad * 8);
      acc[nt] = __builtin_amdgcn_mfma_f32_16x16x32_bf16(ah, bh, acc[nt], 0, 0, 0);
      acc[nt] = __builtin_amdgcn_mfma_f32_16x16x32_bf16(ah, bl, acc[nt], 0, 0, 0);
      acc[nt] = __builtin_amdgcn_mfma_f32_16x16x32_bf16(al, bh, acc[nt], 0, 0, 0);
    }
  }
#pragma unroll
  for (int nt = 0; nt < 4; ++nt)
#pragma unroll
    for (int r = 0; r < 4; ++r) {
      int row = m0 + wv * 16 + quad * 4 + r;
      if (row < M) {
        float f = acc[nt][r];
        unsigned short h = f2bf(f);
        size_t o = (size_t)row * N + n0 + nt * 16 + mrow;
        Ch[o] = h;
        Cl[o] = f2bf(f - bf2f(h));
      }
    }
}

// ---------------- helpers ----------------

__device__ __forceinline__ void ea_fma(float4& v, const float4 ea, const float4* w) {
  v.x += ea.x * w[0].x + ea.y * w[1].x + ea.z * w[2].x + ea.w * w[3].x;
  v.y += ea.x * w[0].y + ea.y * w[1].y + ea.z * w[2].y + ea.w * w[3].y;
  v.z += ea.x * w[0].z + ea.y * w[1].z + ea.z * w[2].z + ea.w * w[3].z;
  v.w += ea.x * w[0].w + ea.y * w[1].w + ea.z * w[2].w + ea.w * w[3].w;
}

__device__ __forceinline__ void leaky4(float4& v) {
  v.x = (v.x > 0.f) ? v.x : 0.2f * v.x;
  v.y = (v.y > 0.f) ? v.y : 0.2f * v.y;
  v.z = (v.z > 0.f) ? v.z : 0.2f * v.z;
  v.w = (v.w > 0.f) ? v.w : 0.2f * v.w;
}

__device__ __forceinline__ void upd4(float& m, float& d, float4& a, float l, const float4 v) {
  float mn = fmaxf(m, l), f = __expf(m - mn), p = __expf(l - mn);
  d = d * f + p;
  a.x = a.x * f + p * v.x; a.y = a.y * f + p * v.y;
  a.z = a.z * f + p * v.z; a.w = a.w * f + p * v.w;
  m = mn;
}

__device__ __forceinline__ void mrg4(float& m, float& d, float4& a, float m2, float d2,
                                     const float4 a2) {
  float M = fmaxf(m, m2), f1 = __expf(m - M), f2 = __expf(m2 - M);
  d = d * f1 + d2 * f2;
  a.x = a.x * f1 + a2.x * f2; a.y = a.y * f1 + a2.y * f2;
  a.z = a.z * f1 + a2.z * f2; a.w = a.w * f1 + a2.w * f2;
  m = M;
}

__device__ __forceinline__ void upd1(float& m, float& d, float& a, float l, float v) {
  float mn = fmaxf(m, l), f = __expf(m - mn), p = __expf(l - mn);
  d = d * f + p; a = a * f + p * v; m = mn;
}

__device__ __forceinline__ void mrg1(float& m, float& d, float& a, float m2, float d2,
                                     float a2) {
  float M = fmaxf(m, m2), f1 = __expf(m - M), f2 = __expf(m2 - M);
  d = d * f1 + d2 * f2; a = a * f1 + a2 * f2; m = M;
}

// ---------------- pass 1: edge logits, EDGE-STREAMING (round-7 form) + bf16-hi gathers ----
// layer 1: wave owns 16 CSR positions; lane = (head, 4-ch group); 2-edge unroll.
// xl = hi plane (stride 512 shorts); xr = same plane + 256.

__global__ __launch_bounds__(256, 1) void edge_logits1(
    const int* __restrict__ srcs, const int* __restrict__ dsts,
    const float4* __restrict__ ea_r, const unsigned short* __restrict__ xh,
    const float* __restrict__ We, const float* __restrict__ att,
    float* __restrict__ logits) {
  int gw = (blockIdx.x * 256 + threadIdx.x) >> 6;
  int lane = threadIdx.x & 63;
  int col = (lane >> 4) * 64 + (lane & 15) * 4;
  int h = lane >> 4;
  bool leader = (lane & 15) == 0;
  float4 we[16];
#pragma unroll
  for (int k = 0; k < 16; ++k) we[k] = *(const float4*)(We + k * 256 + col);
  float4 at = *(const float4*)(att + col);
  int base = gw * 16;
  for (int i = base; i < base + 16; i += 2) {
    int s0 = srcs[i], s1 = srcs[i + 1];
    int d0 = dsts[i], d1 = dsts[i + 1];
    float4 xa = ld_bf4(xh + (size_t)s0 * 512 + col);
    float4 xb = ld_bf4(xh + (size_t)s1 * 512 + col);
    float4 ra = ld_bf4(xh + (size_t)d0 * 512 + 256 + col);
    float4 rb = ld_bf4(xh + (size_t)d1 * 512 + 256 + col);
    const float4* ep = ea_r + (size_t)i * 4;
    float4 p0 = ep[0], p1 = ep[1], p2 = ep[2], p3 = ep[3];
    float4 q0 = ep[4], q1 = ep[5], q2 = ep[6], q3 = ep[7];
    float4 v0, v1;
    v0.x = xa.x + ra.x; v0.y = xa.y + ra.y; v0.z = xa.z + ra.z; v0.w = xa.w + ra.w;
    v1.x = xb.x + rb.x; v1.y = xb.y + rb.y; v1.z = xb.z + rb.z; v1.w = xb.w + rb.w;
    ea_fma(v0, p0, we + 0); ea_fma(v0, p1, we + 4);
    ea_fma(v0, p2, we + 8); ea_fma(v0, p3, we + 12);
    ea_fma(v1, q0, we + 0); ea_fma(v1, q1, we + 4);
    ea_fma(v1, q2, we + 8); ea_fma(v1, q3, we + 12);
    leaky4(v0); leaky4(v1);
    float sA = at.x * v0.x + at.y * v0.y + at.z * v0.z + at.w * v0.w;
    float sB = at.x * v1.x + at.y * v1.y + at.z * v1.z + at.w * v1.w;
#pragma unroll
    for (int off = 8; off >= 1; off >>= 1) {
      sA += __shfl_xor(sA, off);
      sB += __shfl_xor(sB, off);
    }
    if (leader) {
      logits[4 * i + h] = sA;
      logits[4 * (i + 1) + h] = sB;
    }
  }
}

// layer 2 (H=1): 16-lane group per edge, 4 edges per wave-iter; hi-plane stride 128.
__global__ __launch_bounds__(256, 1) void edge_logits2(
    const int* __restrict__ srcs, const int* __restrict__ dsts,
    const float4* __restrict__ ea_r, const unsigned short* __restrict__ xh,
    const float* __restrict__ We, const float* __restrict__ att,
    float* __restrict__ logits) {
  int gw = (blockIdx.x * 256 + threadIdx.x) >> 6;
  int lane = threadIdx.x & 63;
  int g = lane >> 4, q = lane & 15;
  int cb = q * 4;
  float4 we[16];
#pragma unroll
  for (int k = 0; k < 16; ++k) we[k] = *(const float4*)(We + k * 64 + cb);
  float4 at = *(const float4*)(att + cb);
  int base = gw * 32;
  for (int it = 0; it < 8; ++it) {
    int i = base + it * 4 + g;
    int s = srcs[i], d = dsts[i];
    float4 xa = ld_bf4(xh + (size_t)s * 128 + cb);
    float4 ra = ld_bf4(xh + (size_t)d * 128 + 64 + cb);
    const float4* ep = ea_r + (size_t)i * 4;
    float4 p0 = ep[0], p1 = ep[1], p2 = ep[2], p3 = ep[3];
    float4 v;
    v.x = xa.x + ra.x; v.y = xa.y + ra.y; v.z = xa.z + ra.z; v.w = xa.w + ra.w;
    ea_fma(v, p0, we + 0); ea_fma(v, p1, we + 4);
    ea_fma(v, p2, we + 8); ea_fma(v, p3, we + 12);
    leaky4(v);
    float s_ = at.x * v.x + at.y * v.y + at.z * v.z + at.w * v.w;
#pragma unroll
    for (int off = 8; off >= 1; off >>= 1) s_ += __shfl_xor(s_, off);
    if (q == 0) logits[i] = s_;
  }
}

// ---------------- pass 2: thin aggregation, bf16-hi gathers ----------------

__global__ __launch_bounds__(256) void aggregate1(
    const int* __restrict__ srcs, const int* __restrict__ row_ptr,
    const float* __restrict__ logits, const unsigned short* __restrict__ xh,
    const float* __restrict__ bias, unsigned short* __restrict__ h_hi,
    unsigned short* __restrict__ h_lo) {
  int w = threadIdx.x >> 6, lane = threadIdx.x & 63;
  int n = blockIdx.x * 4 + w;
  int col = (lane >> 4) * 64 + (lane & 15) * 4;
  int h = lane >> 4;
  int beg = row_ptr[n], end = row_ptr[n + 1];
  float m0 = -1e30f, m1 = -1e30f, m2 = -1e30f, m3 = -1e30f;
  float d0 = 0.f, d1 = 0.f, d2 = 0.f, d3 = 0.f;
  float4 a0 = {0, 0, 0, 0}, a1 = {0, 0, 0, 0}, a2 = {0, 0, 0, 0}, a3 = {0, 0, 0, 0};
  int i = beg;
  for (; i + 4 <= end; i += 4) {
    int s0 = srcs[i], s1 = srcs[i + 1], s2 = srcs[i + 2], s3 = srcs[i + 3];
    float l0 = logits[4 * i + h];
    float l1 = logits[4 * (i + 1) + h];
    float l2 = logits[4 * (i + 2) + h];
    float l3 = logits[4 * (i + 3) + h];
    float4 x0 = ld_bf4(xh + (size_t)s0 * 512 + col);
    float4 x1 = ld_bf4(xh + (size_t)s1 * 512 + col);
    float4 x2 = ld_bf4(xh + (size_t)s2 * 512 + col);
    float4 x3 = ld_bf4(xh + (size_t)s3 * 512 + col);
    upd4(m0, d0, a0, l0, x0);
    upd4(m1, d1, a1, l1, x1);
    upd4(m2, d2, a2, l2, x2);
    upd4(m3, d3, a3, l3, x3);
  }
  for (; i < end; ++i) {
    int s0 = srcs[i];
    float l0 = logits[4 * i + h];
    float4 x0 = ld_bf4(xh + (size_t)s0 * 512 + col);
    upd4(m0, d0, a0, l0, x0);
  }
  mrg4(m0, d0, a0, m1, d1, a1);
  mrg4(m2, d2, a2, m3, d3, a3);
  mrg4(m0, d0, a0, m2, d2, a2);
  bool has = end > beg;
  float rd = has ? 1.f / d0 : 0.f;
  float4 b4 = *(const float4*)(bias + col);
  float4 o;
  o.x = a0.x * rd + b4.x;
  o.y = a0.y * rd + b4.y;
  o.z = a0.z * rd + b4.z;
  o.w = a0.w * rd + b4.w;
  o.x = (o.x > 0.f) ? o.x : (__expf(o.x) - 1.f);
  o.y = (o.y > 0.f) ? o.y : (__expf(o.y) - 1.f);
  o.z = (o.z > 0.f) ? o.z : (__expf(o.z) - 1.f);
  o.w = (o.w > 0.f) ? o.w : (__expf(o.w) - 1.f);
  ushort4 oh, ol;
  oh.x = f2bf(o.x); ol.x = f2bf(o.x - bf2f(oh.x));
  oh.y = f2bf(o.y); ol.y = f2bf(o.y - bf2f(oh.y));
  oh.z = f2bf(o.z); ol.z = f2bf(o.z - bf2f(oh.z));
  oh.w = f2bf(o.w); ol.w = f2bf(o.w - bf2f(oh.w));
  *(ushort4*)(h_hi + (size_t)n * 256 + col) = oh;
  *(ushort4*)(h_lo + (size_t)n * 256 + col) = ol;
}

__global__ __launch_bounds__(256) void aggregate2(
    const int* __restrict__ srcs, const int* __restrict__ row_ptr,
    const float* __restrict__ logits, const unsigned short* __restrict__ xh,
    const float* __restrict__ bias, float* __restrict__ out) {
  int w = threadIdx.x >> 6, lane = threadIdx.x & 63;
  int n = blockIdx.x * 4 + w;
  int beg = row_ptr[n], end = row_ptr[n + 1];
  float m0 = -1e30f, m1 = -1e30f, m2 = -1e30f, m3 = -1e30f;
  float d0 = 0.f, d1 = 0.f, d2 = 0.f, d3 = 0.f;
  float a0 = 0.f, a1 = 0.f, a2 = 0.f, a3 = 0.f;
  int i = beg;
  for (; i + 4 <= end; i += 4) {
    int s0 = srcs[i], s1 = srcs[i + 1], s2 = srcs[i + 2], s3 = srcs[i + 3];
    float l0 = logits[i], l1 = logits[i + 1], l2 = logits[i + 2], l3 = logits[i + 3];
    float x0 = bf2f(xh[(size_t)s0 * 128 + lane]);
    float x1 = bf2f(xh[(size_t)s1 * 128 + lane]);
    float x2 = bf2f(xh[(size_t)s2 * 128 + lane]);
    float x3 = bf2f(xh[(size_t)s3 * 128 + lane]);
    upd1(m0, d0, a0, l0, x0);
    upd1(m1, d1, a1, l1, x1);
    upd1(m2, d2, a2, l2, x2);
    upd1(m3, d3, a3, l3, x3);
  }
  for (; i < end; ++i) {
    int s0 = srcs[i];
    float l0 = logits[i];
    float x0 = bf2f(xh[(size_t)s0 * 128 + lane]);
    upd1(m0, d0, a0, l0, x0);
  }
  mrg1(m0, d0, a0, m1, d1, a1);
  mrg1(m2, d2, a2, m3, d3, a3);
  mrg1(m0, d0, a0, m2, d2, a2);
  bool has = end > beg;
  float o = (has ? a0 / d0 : 0.f) + bias[lane];
  out[(size_t)n * 64 + lane] = o;
}

// ---------------- launch ----------------

extern "C" void kernel_launch(void* const* d_in, const int* in_sizes, int n_in,
                              void* d_out, int out_size, void* d_ws, size_t ws_size,
                              hipStream_t stream) {
  const float* x    = (const float*)d_in[0];
  const int*   ei   = (const int*)  d_in[1];
  const float* eatt = (const float*)d_in[2];
  const float* Wl1  = (const float*)d_in[3];
  const float* Wr1  = (const float*)d_in[4];
  const float* We1  = (const float*)d_in[5];
  const float* att1 = (const float*)d_in[6];
  const float* b1   = (const float*)d_in[7];
  const float* Wl2  = (const float*)d_in[8];
  const float* Wr2  = (const float*)d_in[9];
  const float* We2  = (const float*)d_in[10];
  const float* att2 = (const float*)d_in[11];
  const float* b2   = (const float*)d_in[12];
  float* out = (float*)d_out;

  char* wsb = (char*)d_ws;
  size_t off = 0;
  auto alloc = [&](size_t bytes) {
    char* p = wsb + off;
    off += (bytes + 255) & ~(size_t)255;
    return p;
  };
  int* counts    = (int*)alloc((size_t)NN * 4);
  int* tmp       = (int*)alloc((size_t)NN * 4);
  int* bsum      = (int*)alloc(32 * 4);
  int* row_ptr   = (int*)alloc((size_t)(NN + 1) * 4);
  int* cursor    = (int*)alloc((size_t)NN * 4);
  int* srcs      = (int*)alloc((size_t)NE * 4);
  int* dsts      = (int*)alloc((size_t)NE * 4);
  float4* ea_r   = (float4*)alloc((size_t)NE * 16 * 4);
  float* logits1 = (float*)alloc((size_t)NE * 4 * 4);
  unsigned short* x_hi  = (unsigned short*)alloc((size_t)NN * 128 * 2);
  unsigned short* x_lo  = (unsigned short*)alloc((size_t)NN * 128 * 2);
  unsigned short* W1th  = (unsigned short*)alloc((size_t)512 * 128 * 2);
  unsigned short* W1tl  = (unsigned short*)alloc((size_t)512 * 128 * 2);
  unsigned short* W2th  = (unsigned short*)alloc((size_t)128 * 256 * 2);
  unsigned short* W2tl  = (unsigned short*)alloc((size_t)128 * 256 * 2);
  unsigned short* h_hi  = (unsigned short*)alloc((size_t)NN * 256 * 2);
  unsigned short* h_lo  = (unsigned short*)alloc((size_t)NN * 256 * 2);
  unsigned short* x1h   = (unsigned short*)alloc((size_t)NN * 512 * 2);
  unsigned short* x1l   = (unsigned short*)alloc((size_t)NN * 512 * 2);
  unsigned short* x2h   = (unsigned short*)alloc((size_t)NN * 128 * 2);
  unsigned short* x2l   = (unsigned short*)alloc((size_t)NN * 128 * 2);
  float* logits2 = logits1;  // alias: logits1 dead after aggregate1

  // CSR by destination (+ srcs/dsts + edge_attr reorder)
  zero_i32<<<(NN + 255) / 256, 256, 0, stream>>>(counts, NN);
  count_dst<<<(NE + 255) / 256, 256, 0, stream>>>(ei, counts);
  scan_local<<<(NN + 1023) / 1024, 1024, 0, stream>>>(counts, tmp, bsum);
  scan_bsum<<<1, 64, 0, stream>>>(bsum, (NN + 1023) / 1024);
  scan_finish<<<(NN + 255) / 256, 256, 0, stream>>>(counts, tmp, bsum, row_ptr, cursor);
  scatter_edges<<<(NE + 255) / 256, 256, 0, stream>>>(ei, (const float4*)eatt, cursor,
                                                      srcs, dsts, ea_r);

  // split-bf16 conversions (W transposed for the B-resident GEMM)
  split_bf16<<<(NN * 128 + 255) / 256, 256, 0, stream>>>(x, x_hi, x_lo, NN * 128);
  cat_split_T<<<(512 * 128 + 255) / 256, 256, 0, stream>>>(Wl1, Wr1, W1th, W1tl, 256, 128,
                                                           512 * 128);
  cat_split_T<<<(128 * 256 + 255) / 256, 256, 0, stream>>>(Wl2, Wr2, W2th, W2tl, 64, 256,
                                                           128 * 256);

  // layer 1
  mfma_gemm_B<128><<<dim3((NN + 63) / 64, 8), 256, 0, stream>>>(
      x_hi, x_lo, W1th, W1tl, x1h, x1l, NN, 512);
  edge_logits1<<<NE / 64, 256, 0, stream>>>(srcs, dsts, ea_r, x1h, We1, att1, logits1);
  aggregate1<<<NN / 4, 256, 0, stream>>>(srcs, row_ptr, logits1, x1h, b1, h_hi, h_lo);

  // layer 2
  mfma_gemm_B<256><<<dim3((NN + 63) / 64, 2), 256, 0, stream>>>(
      h_hi, h_lo, W2th, W2tl, x2h, x2l, NN, 128);
  edge_logits2<<<NE / 128, 256, 0, stream>>>(srcs, dsts, ea_r, x2h, We2, att2, logits2);
  aggregate2<<<NN / 4, 256, 0, stream>>>(srcs, row_ptr, logits2, x2h, b2, out);
}